// Round 9
// baseline (15134.428 us; speedup 1.0000x reference)
//
#include <hip/hip_runtime.h>
#include <hip/hip_bf16.h>

#define TSTEPS 127
#define NBLK 256
#define NVB 250      // 32000/128
#define MROWS 8128   // 127*64

typedef unsigned short u16;
typedef unsigned int u32;
typedef unsigned long long u64;
typedef _Float16 f16;
typedef __attribute__((ext_vector_type(8))) short bf16x8;
typedef __attribute__((ext_vector_type(8))) _Float16 f16x8;
typedef __attribute__((ext_vector_type(8))) unsigned short u16x8;
typedef __attribute__((ext_vector_type(4))) float f32x4;

__device__ __forceinline__ u16 f2h(float f){ f16 h=(f16)f; u16 r; __builtin_memcpy(&r,&h,2); return r; }
__device__ __forceinline__ float h2f(u16 u){ f16 h; __builtin_memcpy(&h,&u,2); return (float)h; }
__device__ __forceinline__ float us2f(u16 u){ union{float f;u32 i;}v; v.i=(u32)u<<16; return v.f; }
__device__ __forceinline__ u16 f2us(float f){ __hip_bfloat16 h=__float2bfloat16(f); u16 r; __builtin_memcpy(&r,&h,2); return r; }
__device__ __forceinline__ void split2(float x, u16& hi, u16& lo){
  u16 h = f2us(x); lo = f2us(x - us2f(h)); hi = h;
}

// ---- agent-scope (cache-bypassing) relaxed atomics for mutable shared state ----
__device__ __forceinline__ u64 ldg64(const u64* p){
  return __hip_atomic_load((u64*)p, __ATOMIC_RELAXED, __HIP_MEMORY_SCOPE_AGENT);
}
__device__ __forceinline__ float ldgf(const float* p){
  return __hip_atomic_load((float*)p, __ATOMIC_RELAXED, __HIP_MEMORY_SCOPE_AGENT);
}
__device__ __forceinline__ void stg64(u64* p, u64 v){
  __hip_atomic_store(p, v, __ATOMIC_RELAXED, __HIP_MEMORY_SCOPE_AGENT);
}
__device__ __forceinline__ void stgf(float* p, float v){
  __hip_atomic_store(p, v, __ATOMIC_RELAXED, __HIP_MEMORY_SCOPE_AGENT);
}
__device__ __forceinline__ f16x8 mk8h(u64 a, u64 b){
  union { u64 q[2]; f16x8 v; } u; u.q[0]=a; u.q[1]=b; return u.v;
}

// flag-array barrier: only wave 0 spins (lane l watches 4 flags), no invalidate
__device__ __forceinline__ void gbar(u32* flags, u32 token){
  asm volatile("s_waitcnt vmcnt(0) lgkmcnt(0)" ::: "memory");
  __syncthreads();
  if (threadIdx.x == 0)
    __hip_atomic_store(&flags[blockIdx.x*32], token, __ATOMIC_RELAXED, __HIP_MEMORY_SCOPE_AGENT);
  if (threadIdx.x < 64){
    const int l = threadIdx.x;
    for (;;){
      bool ok = true;
#pragma unroll
      for (int i=0;i<4;i++)
        ok &= (__hip_atomic_load(&flags[(l*4+i)*32], __ATOMIC_RELAXED, __HIP_MEMORY_SCOPE_AGENT) >= token);
      if (__all(ok)) break;
      __builtin_amdgcn_s_sleep(8);
    }
  }
  __syncthreads();
}

// ---------------- prep kernels ----------------
__global__ void p_wcat(const float* __restrict__ Watt, const float* __restrict__ Wu,
                       float* __restrict__ Wcat){
  int idx = blockIdx.x*256 + threadIdx.x;      // 2048*2048
  int n = idx >> 11, k = idx & 2047;
  Wcat[idx] = (n < 1024) ? Watt[idx] : Wu[(size_t)(n-1024)*3072 + k];
}

// WY: Y-part of Wih in j'-order (j' = jj*4+g, j = g*1024+jj), split hi/lo (for k_gy)
__global__ void p_wy(const float* __restrict__ Wih, u16* __restrict__ WYh, u16* __restrict__ WYl){
  int k = blockIdx.x*256 + threadIdx.x;        // 512
  int rp = blockIdx.y;                         // 4096
  int j = (rp & 3)*1024 + (rp >> 2);
  float v = Wih[(size_t)j*1536 + 1024 + k];
  u16 hi, lo; split2(v, hi, lo);
  WYh[(size_t)rp*512 + k] = hi; WYl[(size_t)rp*512 + k] = lo;
}

__global__ void p_wuh(const float* __restrict__ Wu, u16* __restrict__ Wh){
  int k = blockIdx.x*256 + threadIdx.x;        // 1024
  int j = blockIdx.y;                          // 1024
  Wh[(size_t)j*1024 + k] = f2h(Wu[(size_t)j*3072 + 2048 + k]);
}

__global__ void p_y(const int* __restrict__ ids, const float* __restrict__ Etgt,
                    u16* __restrict__ Yh, u16* __restrict__ Yl){
  int e0 = blockIdx.x*256 + threadIdx.x;       // 512
  int row = blockIdx.y;                        // 8192
  int id = ids[row];
  float v = Etgt[(size_t)id*512 + e0];
  u16 hi, lo; split2(v, hi, lo);
  Yh[(size_t)row*512 + e0] = hi; Yl[(size_t)row*512 + e0] = lo;
}

__global__ void p_init(const float* __restrict__ h0,
                       u16* __restrict__ hf, u16* __restrict__ of,
                       u32* __restrict__ flags){
  int idx = blockIdx.x*256 + threadIdx.x;
  if (idx < 65536){
    hf[idx] = f2h(h0[idx]);     // parity-0 buffer
    of[idx] = 0;
  } else if (idx < 65536 + 8192){
    flags[idx - 65536] = 0;
  }
}

// ---------------- enc_proj + Vu GEMM (fp32 in, f16 out): M=16384 N=2048 K=2048 ----
union SharedU {
  struct { u16 a[128*72]; u16 b[128*72]; } st;
  float cc[128*128];
};

__global__ __launch_bounds__(256) void k_gemm32(
    const float* __restrict__ A, const float* __restrict__ Bm,
    const float* __restrict__ bias, u16* __restrict__ ep, u16* __restrict__ vu)
{
  __shared__ SharedU sm;
  const int tid = threadIdx.x;
  const int lane = tid & 63, w = tid >> 6;
  const int wm = w >> 1, wn = w & 1;
  int lw = blockIdx.y * gridDim.x + blockIdx.x;       // 2048
  int swz = (lw & 7)*256 + (lw >> 3);
  const int n0 = (swz & 15) * 128, m0 = (swz >> 4) * 128;
  f32x4 acc[4][4];
#pragma unroll
  for (int i=0;i<4;i++)
#pragma unroll
    for (int j=0;j<4;j++) acc[i][j] = (f32x4)(0.f);

  for (int k0 = 0; k0 < 2048; k0 += 64) {
    __syncthreads();
#pragma unroll
    for (int i=0;i<8;i++){
      int idx = tid + i*256;
      int r = idx >> 4, c4 = idx & 15;
      float4 va = *(const float4*)(&A[(size_t)(m0+r)*2048 + k0 + c4*4]);
      ushort4 sa; sa.x=f2h(va.x); sa.y=f2h(va.y); sa.z=f2h(va.z); sa.w=f2h(va.w);
      *(ushort4*)(&sm.st.a[r*72 + c4*4]) = sa;
      float4 vb = *(const float4*)(&Bm[(size_t)(n0+r)*2048 + k0 + c4*4]);
      ushort4 sb; sb.x=f2h(vb.x); sb.y=f2h(vb.y); sb.z=f2h(vb.z); sb.w=f2h(vb.w);
      *(ushort4*)(&sm.st.b[r*72 + c4*4]) = sb;
    }
    __syncthreads();
#pragma unroll
    for (int kk = 0; kk < 64; kk += 32) {
      f16x8 af[4], bfr[4];
      int krow = kk + ((lane >> 4) << 3);
#pragma unroll
      for (int m4=0;m4<4;m4++)
        af[m4] = *(const f16x8*)(&sm.st.a[(wm*64 + m4*16 + (lane & 15))*72 + krow]);
#pragma unroll
      for (int n4=0;n4<4;n4++)
        bfr[n4] = *(const f16x8*)(&sm.st.b[(wn*64 + n4*16 + (lane & 15))*72 + krow]);
#pragma unroll
      for (int m4=0;m4<4;m4++)
#pragma unroll
        for (int n4=0;n4<4;n4++)
          acc[m4][n4] = __builtin_amdgcn_mfma_f32_16x16x32_f16(af[m4], bfr[n4], acc[m4][n4], 0,0,0);
    }
  }
  __syncthreads();
#pragma unroll
  for (int m4=0;m4<4;m4++)
#pragma unroll
    for (int n4=0;n4<4;n4++)
#pragma unroll
      for (int i=0;i<4;i++){
        int row = wm*64 + m4*16 + ((lane>>4)<<2) + i;
        int col = wn*64 + n4*16 + (lane&15);
        sm.cc[row*128 + col] = acc[m4][n4][i];
      }
  __syncthreads();
  for (int idx = tid; idx < 128*128; idx += 256) {
    int row = idx >> 7, col = idx & 127;
    int gm = m0 + row, gn = n0 + col;
    float vv = sm.cc[idx];
    if (gn < 1024) { vv += bias[gn]; ep[(size_t)gm*1024 + gn] = f2h(vv); }
    else           { vu[(size_t)gm*1024 + (gn-1024)] = f2h(vv); }
  }
}

// ---------------- gY GEMM: gY[(t*64+b)][j'] = Y[t,b,:]·WY[j',:] -> f16 ----
__global__ __launch_bounds__(256) void k_gy(
    const u16* __restrict__ Ah, const u16* __restrict__ Al,
    const u16* __restrict__ Bh, const u16* __restrict__ Bl,
    u16* __restrict__ gY)
{
  __shared__ u16 sah[128*40], sal[128*40], sbh[128*40], sbl[128*40];
  const int tid = threadIdx.x;
  const int lane = tid & 63, w = tid >> 6;
  const int wm = w >> 1, wn = w & 1;
  const int l15 = lane & 15, q8 = (lane>>4)*8;
  int lw = blockIdx.y * gridDim.x + blockIdx.x;       // 2048
  int swz = (lw & 7)*256 + (lw >> 3);
  const int n0 = (swz & 31)*128, m0 = (swz >> 5)*128;
  f32x4 acc[4][4];
#pragma unroll
  for (int i=0;i<4;i++)
#pragma unroll
    for (int j=0;j<4;j++) acc[i][j] = (f32x4)(0.f);

  for (int k0 = 0; k0 < 512; k0 += 32){
    __syncthreads();
#pragma unroll
    for (int i=0;i<8;i++){
      int idx = i*256 + tid;          // 2048 = 4 mats x 512 u16x8
      int mat = idx >> 9, sub = idx & 511;
      int r = sub >> 2, c8 = (sub & 3)*8;
      const u16* src = (mat==0)?Ah:(mat==1)?Al:(mat==2)?Bh:Bl;
      size_t base = (mat<2 ? (size_t)(m0+r)*512 : (size_t)(n0+r)*512) + k0 + c8;
      u16x8 v = *(const u16x8*)(src + base);
      u16* dst = (mat==0)?sah:(mat==1)?sal:(mat==2)?sbh:sbl;
      *(u16x8*)(&dst[r*40 + c8]) = v;
    }
    __syncthreads();
    bf16x8 ah[4], al2[4], bh[4], bl2[4];
#pragma unroll
    for (int m4=0;m4<4;m4++){
      ah[m4]  = *(const bf16x8*)(&sah[(wm*64+m4*16+l15)*40 + q8]);
      al2[m4] = *(const bf16x8*)(&sal[(wm*64+m4*16+l15)*40 + q8]);
    }
#pragma unroll
    for (int n4=0;n4<4;n4++){
      bh[n4]  = *(const bf16x8*)(&sbh[(wn*64+n4*16+l15)*40 + q8]);
      bl2[n4] = *(const bf16x8*)(&sbl[(wn*64+n4*16+l15)*40 + q8]);
    }
#pragma unroll
    for (int m4=0;m4<4;m4++)
#pragma unroll
      for (int n4=0;n4<4;n4++){
        acc[m4][n4] = __builtin_amdgcn_mfma_f32_16x16x32_bf16(ah[m4],  bh[n4],  acc[m4][n4], 0,0,0);
        acc[m4][n4] = __builtin_amdgcn_mfma_f32_16x16x32_bf16(al2[m4], bh[n4],  acc[m4][n4], 0,0,0);
        acc[m4][n4] = __builtin_amdgcn_mfma_f32_16x16x32_bf16(ah[m4],  bl2[n4], acc[m4][n4], 0,0,0);
      }
  }
#pragma unroll
  for (int m4=0;m4<4;m4++)
#pragma unroll
    for (int n4=0;n4<4;n4++)
#pragma unroll
      for (int i=0;i<4;i++){
        int gm = m0 + wm*64 + m4*16 + ((lane>>4)<<2) + i;
        int gn = n0 + wn*64 + n4*16 + l15;
        gY[(size_t)gm*4096 + gn] = f2h(acc[m4][n4][i]);
      }
}

// ---------------- persistent recurrence kernel ----------------
// block = (jt = blk>>2 owns 64 j'-rows, bg = blk&3 owns 16 b's)
// waves (khalf = w>>1, jhalf = w&1); gate weights in REGISTERS (f16x8 wreg[2][32]);
// x = [o|h] staged into swizzled LDS by a pipelined bypass-copy.
struct alignas(16) LoopShared {
  u16 xs[16*2048];                       // 64 KB staged x, byte ^= ((b&7)<<4)
  union {
    struct { float psum[2][64][8]; u16 hstage[16][16]; } p1;
    struct { float al[256]; float pared[4][256]; float red[8]; } p3;
  } u;
};

__global__ __launch_bounds__(256, 1) void k_loop(
    const float* __restrict__ Wih, const float* __restrict__ Whh,
    const float* __restrict__ c0g,
    const u16* __restrict__ Wuh16, const u16* __restrict__ gY,
    const u16* __restrict__ ep, const u16* __restrict__ vuu,
    u16* __restrict__ hf, u16* __restrict__ of,
    float* __restrict__ ebuf, float* __restrict__ phB,
    u16* __restrict__ comb, u32* __restrict__ flags)
{
  __shared__ LoopShared sh;
  const int tid = threadIdx.x, blk = blockIdx.x;
  const int lane = tid & 63, w = tid >> 6;
  const int l15 = lane & 15, q = lane >> 4;
  const int jt = blk >> 2, bg = blk & 3;
  const int jhalf = w & 1, khalf = w >> 1;

  // ---- one-time: this wave's quarter of 64 j'-rows into registers (f16) ----
  f16x8 wreg[2][32];
#pragma unroll
  for (int rb=0;rb<2;rb++){
    int jp = jt*64 + jhalf*32 + rb*16 + l15;
    int j  = (jp & 3)*1024 + (jp >> 2);
#pragma unroll
    for (int kt=0;kt<32;kt++){
      int k = khalf*1024 + kt*32 + q*8;
      const float* src = (k < 1536) ? &Wih[(size_t)j*1536 + k]
                                    : &Whh[(size_t)j*1024 + (k-1536)];
      float4 a4 = *(const float4*)src;
      float4 b4 = *(const float4*)(src + 4);
      union { f16x8 v; f16 e[8]; } wv;
      wv.e[0]=(f16)a4.x; wv.e[1]=(f16)a4.y; wv.e[2]=(f16)a4.z; wv.e[3]=(f16)a4.w;
      wv.e[4]=(f16)b4.x; wv.e[5]=(f16)b4.y; wv.e[6]=(f16)b4.z; wv.e[7]=(f16)b4.w;
      wreg[rb][kt] = wv.v;
    }
  }
  float cReg[2] = {0.f, 0.f};
  if (w < 2){
#pragma unroll
    for (int rb=0;rb<2;rb++)
      cReg[rb] = c0g[(size_t)(bg*16+l15)*1024 + jt*16 + w*8 + rb*4 + q];
  }
  __syncthreads();

  for (int t = 0; t < TSTEPS; ++t){
    const int p = t & 1;
    const u16* hP = hf + p*65536;
    u16* hN = hf + (p^1)*65536;

    // ======== P1: stage x=[o|h] into LDS (pipelined bypass copy) ========
    {
      const u64* osrc = (const u64*)of + (size_t)(bg*16)*256;
      const u64* hsrc = (const u64*)hP + (size_t)(bg*16)*256;
#pragma unroll
      for (int i=0;i<32;i++){
        const int bl = i >> 1;
        const int k4 = (i & 1)*256 + tid;
        u64 v = (i & 1) ? ldg64(hsrc + (size_t)bl*256 + tid)
                        : ldg64(osrc + (size_t)bl*256 + tid);
        int dst = (bl*4096 + k4*8) ^ ((bl & 7) << 4);
        *(u64*)((char*)sh.xs + dst) = v;
      }
    }
    __syncthreads();
    // ======== P1: gates MFMA from LDS x + reg weights ========
    {
      f32x4 acc0 = (f32x4)(0.f), acc1 = (f32x4)(0.f);
#pragma unroll
      for (int kt=0; kt<32; ++kt){
        int byteoff = (l15*4096 + khalf*2048 + kt*64 + q*16) ^ ((l15 & 7) << 4);
        f16x8 xf = *(const f16x8*)((const char*)sh.xs + byteoff);
        acc0 = __builtin_amdgcn_mfma_f32_16x16x32_f16(wreg[0][kt], xf, acc0, 0,0,0);
        acc1 = __builtin_amdgcn_mfma_f32_16x16x32_f16(wreg[1][kt], xf, acc1, 0,0,0);
      }
      if (w >= 2){
        float* ps_ = &sh.u.p1.psum[jhalf][lane][0];
#pragma unroll
        for (int i=0;i<4;i++){ ps_[i] = acc0[i]; ps_[4+i] = acc1[i]; }
      }
      __syncthreads();
      if (w < 2){
        const float* ps_ = &sh.u.p1.psum[w][lane][0];
        const int b = bg*16 + l15;
        const u16* gb = gY + ((size_t)(t*64 + b))*4096 + jt*64 + w*32 + q*4;
        ushort4 g0 = *(const ushort4*)(gb);
        ushort4 g1 = *(const ushort4*)(gb + 16);
        u16 hbits[2];
        {
          float gi = acc0[0]+ps_[0]+h2f(g0.x), gf = acc0[1]+ps_[1]+h2f(g0.y);
          float gg = acc0[2]+ps_[2]+h2f(g0.z), go = acc0[3]+ps_[3]+h2f(g0.w);
          gi = 1.f/(1.f+expf(-gi)); gf = 1.f/(1.f+expf(-gf));
          gg = tanhf(gg);           go = 1.f/(1.f+expf(-go));
          float cn = gf*cReg[0] + gi*gg; cReg[0] = cn;
          hbits[0] = f2h(go*tanhf(cn));
        }
        {
          float gi = acc1[0]+ps_[4]+h2f(g1.x), gf = acc1[1]+ps_[5]+h2f(g1.y);
          float gg = acc1[2]+ps_[6]+h2f(g1.z), go = acc1[3]+ps_[7]+h2f(g1.w);
          gi = 1.f/(1.f+expf(-gi)); gf = 1.f/(1.f+expf(-gf));
          gg = tanhf(gg);           go = 1.f/(1.f+expf(-go));
          float cn = gf*cReg[1] + gi*gg; cReg[1] = cn;
          hbits[1] = f2h(go*tanhf(cn));
        }
        sh.u.p1.hstage[l15][w*8 + q]     = hbits[0];
        sh.u.p1.hstage[l15][w*8 + 4 + q] = hbits[1];
      }
      __syncthreads();
      if (tid < 64){
        int bl = tid >> 2, sub = tid & 3;
        u64 v = *(const u64*)&sh.u.p1.hstage[bl][sub*4];
        stg64((u64*)hN + (size_t)(bg*16 + bl)*256 + jt*4 + sub, v);
      }
    }
    gbar(flags, (u32)(t*3 + 1));

    // ======== P2: ph MFMA (blocks 0..15) | e_t (blocks 16..255) ========
    if (blk < 16){
      const int jrow = blk*64 + w*16 + l15;
      const u16* wp = Wuh16 + (size_t)jrow*1024;
      f32x4 pacc[4];
#pragma unroll
      for (int i=0;i<4;i++) pacc[i] = (f32x4)(0.f);
#pragma unroll 2
      for (int kt = 0; kt < 32; ++kt){
        f16x8 bfr = *(const f16x8*)(wp + kt*32 + q*8);
#pragma unroll
        for (int m=0;m<4;m++){
          const u64* px = (const u64*)hN + (size_t)(m*16+l15)*256 + kt*8 + q*2;
          f16x8 xf = mk8h(ldg64(px), ldg64(px+1));
          pacc[m] = __builtin_amdgcn_mfma_f32_16x16x32_f16(xf, bfr, pacc[m], 0,0,0);
        }
      }
#pragma unroll
      for (int m=0;m<4;m++)
#pragma unroll
        for (int i=0;i<4;i++){
          int bb = m*16 + q*4 + i;
          stgf(phB + (size_t)bb*1024 + jrow, pacc[m][i]);
        }
    } else {
      for (int u2 = blk - 16; u2 < 256; u2 += 240){
        const int ab = u2 >> 2, sl = u2 & 3;
        float hr[64];
        {
          const u64* hp = (const u64*)hN + (size_t)ab*256 + l15*16;
#pragma unroll
          for (int i=0;i<16;i++){
            union{u64 q_; u16 s[4];} uu; uu.q_ = ldg64(hp + i);
#pragma unroll
            for (int e=0;e<4;e++) hr[i*4+e] = h2f(uu.s[e]);
          }
        }
        const int rbase = sl*64 + w*16;
#pragma unroll
        for (int rg = 0; rg < 4; rg++){
          int s = rbase + rg*4 + q;
          const u16x8* row = (const u16x8*)(ep + ((size_t)(ab*256 + s))*1024 + l15*64);
          float a = 0.f;
#pragma unroll
          for (int j=0;j<8;j++){
            u16x8 v = row[j];
#pragma unroll
            for (int e=0;e<8;e++) a += h2f(v[e]) * hr[j*8+e];
          }
          a += __shfl_xor(a, 1); a += __shfl_xor(a, 2);
          a += __shfl_xor(a, 4); a += __shfl_xor(a, 8);
          if (l15 == 0) stgf(ebuf + ab*256 + s, a);
        }
      }
    }
    gbar(flags, (u32)(t*3 + 2));

    // ======== P3: softmax + pa + o_t (block = (ab, jq)) ========
    {
      const int ab = blk >> 2, jq = blk & 3;
      float x = ldgf(ebuf + ab*256 + tid);
      float m_ = x;
#pragma unroll
      for (int off=32; off; off>>=1) m_ = fmaxf(m_, __shfl_xor(m_, off));
      if (lane == 0) sh.u.p3.red[w] = m_;
      __syncthreads();
      m_ = fmaxf(fmaxf(sh.u.p3.red[0],sh.u.p3.red[1]), fmaxf(sh.u.p3.red[2],sh.u.p3.red[3]));
      float pv = expf(x - m_);
      float sv = pv;
#pragma unroll
      for (int off=32; off; off>>=1) sv += __shfl_xor(sv, off);
      if (lane == 0) sh.u.p3.red[4+w] = sv;
      __syncthreads();
      float tot = sh.u.p3.red[4]+sh.u.p3.red[5]+sh.u.p3.red[6]+sh.u.p3.red[7];
      sh.u.p3.al[tid] = pv / tot;
      __syncthreads();
      float a0=0.f, a1=0.f, a2=0.f, a3=0.f;
      const u16* vb = vuu + ((size_t)(ab*256) + w*64)*1024 + jq*256 + lane*4;
      for (int s2=0; s2<64; s2++){
        float aa = sh.u.p3.al[w*64 + s2];
        ushort4 v = *(const ushort4*)(vb + (size_t)s2*1024);
        a0 += aa*h2f(v.x); a1 += aa*h2f(v.y); a2 += aa*h2f(v.z); a3 += aa*h2f(v.w);
      }
      float4 o4; o4.x=a0; o4.y=a1; o4.z=a2; o4.w=a3;
      *(float4*)(&sh.u.p3.pared[w][lane*4]) = o4;
      __syncthreads();
      if (tid < 64){
        const int col = tid*4;
        union{u64 q_; u16 s[4];} uo;
        ushort4 cw;
#pragma unroll
        for (int i=0;i<4;i++){
          float pa = sh.u.p3.pared[0][col+i] + sh.u.p3.pared[1][col+i]
                   + sh.u.p3.pared[2][col+i] + sh.u.p3.pared[3][col+i];
          pa += ldgf(phB + (size_t)ab*1024 + jq*256 + col + i);
          u16 ob = f2h(tanhf(pa));
          uo.s[i] = ob; (&cw.x)[i] = ob;
        }
        stg64((u64*)of + (size_t)ab*256 + jq*64 + tid, uo.q_);
        *(ushort4*)(comb + (size_t)(t*64 + ab)*1024 + jq*256 + col) = cw;
      }
    }
    gbar(flags, (u32)(t*3 + 3));
  }
}

// ---------------- vocab GEMM (comb f16, Wv fp32 converted in-loader) ----------------
__global__ __launch_bounds__(256) void k_gemm16(
    const u16* __restrict__ A, const float* __restrict__ Bm,
    const float* __restrict__ bias,
    float* __restrict__ pm, float* __restrict__ ps,
    float* __restrict__ gl, const int* __restrict__ ids)
{
  __shared__ SharedU sm;
  const int tid = threadIdx.x;
  const int lane = tid & 63, w = tid >> 6;
  const int wm = w >> 1, wn = w & 1;
  int lw = blockIdx.y * 250 + blockIdx.x;        // 16000
  int swz = (lw & 7)*2000 + (lw >> 3);
  const int n0 = (swz % 250) * 128, m0 = (swz / 250) * 128;
  f32x4 acc[4][4];
#pragma unroll
  for (int i=0;i<4;i++)
#pragma unroll
    for (int j=0;j<4;j++) acc[i][j] = (f32x4)(0.f);

  for (int k0 = 0; k0 < 1024; k0 += 64) {
    __syncthreads();
#pragma unroll
    for (int i=0;i<8;i++){
      int idx = i*256 + tid;
      int half = idx >> 10, id2 = idx & 1023;
      int r = id2 >> 3, c8 = (id2 & 7)*8;
      if (half == 0){
        int gm = m0 + r;
        u16x8 v = {0,0,0,0,0,0,0,0};
        if (gm < MROWS) v = *(const u16x8*)(A + (size_t)gm*1024 + k0 + c8);
        *(u16x8*)(&sm.st.a[r*72 + c8]) = v;
      } else {
        const float* src = Bm + (size_t)(n0 + r)*1024 + k0 + c8;
        float4 a4 = *(const float4*)src;
        float4 b4 = *(const float4*)(src + 4);
        ushort4 ha; ha.x=f2h(a4.x); ha.y=f2h(a4.y); ha.z=f2h(a4.z); ha.w=f2h(a4.w);
        ushort4 hb; hb.x=f2h(b4.x); hb.y=f2h(b4.y); hb.z=f2h(b4.z); hb.w=f2h(b4.w);
        *(ushort4*)(&sm.st.b[r*72 + c8]) = ha;
        *(ushort4*)(&sm.st.b[r*72 + c8 + 4]) = hb;
      }
    }
    __syncthreads();
#pragma unroll
    for (int kk = 0; kk < 64; kk += 32) {
      f16x8 af[4], bfr[4];
      int krow = kk + ((lane >> 4) << 3);
#pragma unroll
      for (int m4=0;m4<4;m4++)
        af[m4] = *(const f16x8*)(&sm.st.a[(wm*64 + m4*16 + (lane & 15))*72 + krow]);
#pragma unroll
      for (int n4=0;n4<4;n4++)
        bfr[n4] = *(const f16x8*)(&sm.st.b[(wn*64 + n4*16 + (lane & 15))*72 + krow]);
#pragma unroll
      for (int m4=0;m4<4;m4++)
#pragma unroll
        for (int n4=0;n4<4;n4++)
          acc[m4][n4] = __builtin_amdgcn_mfma_f32_16x16x32_f16(af[m4], bfr[n4], acc[m4][n4], 0,0,0);
    }
  }
  __syncthreads();
#pragma unroll
  for (int m4=0;m4<4;m4++)
#pragma unroll
    for (int n4=0;n4<4;n4++)
#pragma unroll
      for (int i=0;i<4;i++){
        int row = wm*64 + m4*16 + ((lane>>4)<<2) + i;
        int col = wn*64 + n4*16 + (lane&15);
        sm.cc[row*128 + col] = acc[m4][n4][i];
      }
  __syncthreads();

  if (tid < 128) {
    int row = tid, gm = m0 + row;
    if (gm < MROWS) {
      float mx = -1e30f;
      for (int j=0;j<128;j++){
        int col = (row + j) & 127;
        float x = sm.cc[row*128+col] + bias[n0+col];
        mx = fmaxf(mx, x);
      }
      float sum = 0.f;
      for (int j=0;j<128;j++){
        int col = (row + j) & 127;
        float x = sm.cc[row*128+col] + bias[n0+col];
        sum += expf(x - mx);
      }
      pm[(size_t)gm*NVB + n0/128] = mx;
      ps[(size_t)gm*NVB + n0/128] = sum;
      int g = ids[gm + 64];
      unsigned d = (unsigned)(g - n0);
      if (d < 128u) gl[gm] = sm.cc[row*128 + (int)d] + bias[g];
    }
  }
}

// ---------------- final reduce ----------------
__global__ void k_reduce(const float* __restrict__ pm, const float* __restrict__ ps,
                         const float* __restrict__ gl, const int* __restrict__ ids,
                         float* __restrict__ out)
{
  int b = blockIdx.x, tid = threadIdx.x;
  int lane = tid & 63, w = tid >> 6;
  __shared__ float wacc[4];
  float accum = 0.f;
  for (int t = w; t < TSTEPS; t += 4) {
    int r = t*64 + b;
    const float* pmr = pm + (size_t)r*NVB;
    const float* psr = ps + (size_t)r*NVB;
    float mx = -1e30f;
    for (int p2 = lane; p2 < NVB; p2 += 64) mx = fmaxf(mx, pmr[p2]);
#pragma unroll
    for (int off=32; off; off>>=1) mx = fmaxf(mx, __shfl_xor(mx, off));
    float sm = 0.f;
    for (int p2 = lane; p2 < NVB; p2 += 64) sm += psr[p2] * expf(pmr[p2] - mx);
#pragma unroll
    for (int off=32; off; off>>=1) sm += __shfl_xor(sm, off);
    if (lane == 0) {
      int g = ids[r + 64];
      if (g != 0) accum += gl[r] - (mx + logf(sm));
    }
  }
  if (lane == 0) wacc[w] = accum;
  __syncthreads();
  if (tid == 0) out[b] = wacc[0]+wacc[1]+wacc[2]+wacc[3];
}

// ---------------- host ----------------
extern "C" void kernel_launch(void* const* d_in, const int* in_sizes, int n_in,
                              void* d_out, int out_size, void* d_ws, size_t ws_size,
                              hipStream_t stream)
{
  const int*   ids  = (const int*)d_in[0];
  const float* vc   = (const float*)d_in[1];
  const float* h0   = (const float*)d_in[2];
  const float* c0   = (const float*)d_in[3];
  const float* Etgt = (const float*)d_in[4];
  const float* Watt = (const float*)d_in[5];
  const float* batt = (const float*)d_in[6];
  const float* Wih  = (const float*)d_in[7];
  const float* Whh  = (const float*)d_in[8];
  const float* Wu   = (const float*)d_in[9];
  const float* Wv   = (const float*)d_in[10];
  const float* bv   = (const float*)d_in[11];
  float* out = (float*)d_out;

  char* p = (char*)d_ws;
  auto alloc = [&](size_t bytes)->char* {
    char* r = p; p += (bytes + 255) & ~(size_t)255; return r;
  };
  u32* flags = (u32*)alloc(32768);
  u16* Yh    = (u16*)alloc((size_t)8192*512*2);
  u16* Yl    = (u16*)alloc((size_t)8192*512*2);
  u16* WYh   = (u16*)alloc((size_t)4096*512*2);
  u16* WYl   = (u16*)alloc((size_t)4096*512*2);
  u16* Wuh16 = (u16*)alloc((size_t)1024*1024*2);
  float* Wcat= (float*)alloc((size_t)2048*2048*4);
  u16* ep    = (u16*)alloc((size_t)64*256*1024*2);
  u16* vuu   = (u16*)alloc((size_t)64*256*1024*2);
  u16* comb  = (u16*)alloc((size_t)8192*1024*2);
  u16* gY    = (u16*)alloc((size_t)8192*4096*2);
  u16* hfbuf = (u16*)alloc((size_t)2*65536*2);
  u16* ofbuf = (u16*)alloc(65536*2);
  float* ebuf= (float*)alloc((size_t)64*256*4);
  float* phB = (float*)alloc((size_t)64*1024*4);
  float* pm  = (float*)alloc((size_t)MROWS*NVB*4);
  float* ps  = (float*)alloc((size_t)MROWS*NVB*4);
  float* gl  = (float*)alloc((size_t)MROWS*4);

  p_init<<<288, 256, 0, stream>>>(h0, hfbuf, ofbuf, flags);
  p_wcat<<<(2048*2048)/256, 256, 0, stream>>>(Watt, Wu, Wcat);
  p_wy<<<dim3(2, 4096), 256, 0, stream>>>(Wih, WYh, WYl);
  p_wuh<<<dim3(4, 1024), 256, 0, stream>>>(Wu, Wuh16);
  p_y<<<dim3(2, 8192), 256, 0, stream>>>(ids, Etgt, Yh, Yl);

  k_gemm32<<<dim3(16, 128), 256, 0, stream>>>(vc, Wcat, batt, ep, vuu);
  k_gy<<<dim3(32, 64), 256, 0, stream>>>(Yh, Yl, WYh, WYl, gY);

  k_loop<<<NBLK, 256, 0, stream>>>(Wih, Whh, c0, Wuh16, gY, ep, vuu,
                                   hfbuf, ofbuf, ebuf, phB, comb, flags);

  k_gemm16<<<dim3(NVB, 64), 256, 0, stream>>>(comb, Wv, bv, pm, ps, gl, ids);
  k_reduce<<<64, 256, 0, stream>>>(pm, ps, gl, ids, out);
}

// Round 10
// 14379.390 us; speedup vs baseline: 1.0525x; 1.0525x over previous
//
#include <hip/hip_runtime.h>
#include <hip/hip_bf16.h>

#define TSTEPS 127
#define NBLK 256
#define NVB 250      // 32000/128
#define MROWS 8128   // 127*64

typedef unsigned short u16;
typedef unsigned int u32;
typedef unsigned long long u64;
typedef _Float16 f16;
typedef __attribute__((ext_vector_type(8))) short bf16x8;
typedef __attribute__((ext_vector_type(8))) _Float16 f16x8;
typedef __attribute__((ext_vector_type(8))) unsigned short u16x8;
typedef __attribute__((ext_vector_type(4))) float f32x4;

__device__ __forceinline__ u16 f2h(float f){ f16 h=(f16)f; u16 r; __builtin_memcpy(&r,&h,2); return r; }
__device__ __forceinline__ float h2f(u16 u){ f16 h; __builtin_memcpy(&h,&u,2); return (float)h; }
__device__ __forceinline__ float us2f(u16 u){ union{float f;u32 i;}v; v.i=(u32)u<<16; return v.f; }
__device__ __forceinline__ u16 f2us(float f){ __hip_bfloat16 h=__float2bfloat16(f); u16 r; __builtin_memcpy(&r,&h,2); return r; }
__device__ __forceinline__ void split2(float x, u16& hi, u16& lo){
  u16 h = f2us(x); lo = f2us(x - us2f(h)); hi = h;
}

// ---- agent-scope (cache-bypassing) relaxed atomics for mutable shared state ----
__device__ __forceinline__ u64 ldg64(const u64* p){
  return __hip_atomic_load((u64*)p, __ATOMIC_RELAXED, __HIP_MEMORY_SCOPE_AGENT);
}
__device__ __forceinline__ float ldgf(const float* p){
  return __hip_atomic_load((float*)p, __ATOMIC_RELAXED, __HIP_MEMORY_SCOPE_AGENT);
}
__device__ __forceinline__ void stg64(u64* p, u64 v){
  __hip_atomic_store(p, v, __ATOMIC_RELAXED, __HIP_MEMORY_SCOPE_AGENT);
}
__device__ __forceinline__ void stgf(float* p, float v){
  __hip_atomic_store(p, v, __ATOMIC_RELAXED, __HIP_MEMORY_SCOPE_AGENT);
}
__device__ __forceinline__ f16x8 mk8h(u64 a, u64 b){
  union { u64 q[2]; f16x8 v; } u; u.q[0]=a; u.q[1]=b; return u.v;
}

// flag-array barrier: only wave 0 spins (lane l watches 4 flags), no invalidate
__device__ __forceinline__ void gbar(u32* flags, u32 token){
  asm volatile("s_waitcnt vmcnt(0) lgkmcnt(0)" ::: "memory");
  __syncthreads();
  if (threadIdx.x == 0)
    __hip_atomic_store(&flags[blockIdx.x*32], token, __ATOMIC_RELAXED, __HIP_MEMORY_SCOPE_AGENT);
  if (threadIdx.x < 64){
    const int l = threadIdx.x;
    for (;;){
      bool ok = true;
#pragma unroll
      for (int i=0;i<4;i++)
        ok &= (__hip_atomic_load(&flags[(l*4+i)*32], __ATOMIC_RELAXED, __HIP_MEMORY_SCOPE_AGENT) >= token);
      if (__all(ok)) break;
      __builtin_amdgcn_s_sleep(8);
    }
  }
  __syncthreads();
}

// ---------------- prep kernels ----------------
__global__ void p_wcat(const float* __restrict__ Watt, const float* __restrict__ Wu,
                       float* __restrict__ Wcat){
  int idx = blockIdx.x*256 + threadIdx.x;      // 2048*2048
  int n = idx >> 11, k = idx & 2047;
  Wcat[idx] = (n < 1024) ? Watt[idx] : Wu[(size_t)(n-1024)*3072 + k];
}

// WY: Y-part of Wih in j'-order (j' = jj*4+g, j = g*1024+jj), split hi/lo (for k_gy)
__global__ void p_wy(const float* __restrict__ Wih, u16* __restrict__ WYh, u16* __restrict__ WYl){
  int k = blockIdx.x*256 + threadIdx.x;        // 512
  int rp = blockIdx.y;                         // 4096
  int j = (rp & 3)*1024 + (rp >> 2);
  float v = Wih[(size_t)j*1536 + 1024 + k];
  u16 hi, lo; split2(v, hi, lo);
  WYh[(size_t)rp*512 + k] = hi; WYl[(size_t)rp*512 + k] = lo;
}

__global__ void p_wuh(const float* __restrict__ Wu, u16* __restrict__ Wh){
  int k = blockIdx.x*256 + threadIdx.x;        // 1024
  int j = blockIdx.y;                          // 1024
  Wh[(size_t)j*1024 + k] = f2h(Wu[(size_t)j*3072 + 2048 + k]);
}

__global__ void p_y(const int* __restrict__ ids, const float* __restrict__ Etgt,
                    u16* __restrict__ Yh, u16* __restrict__ Yl){
  int e0 = blockIdx.x*256 + threadIdx.x;       // 512
  int row = blockIdx.y;                        // 8192
  int id = ids[row];
  float v = Etgt[(size_t)id*512 + e0];
  u16 hi, lo; split2(v, hi, lo);
  Yh[(size_t)row*512 + e0] = hi; Yl[(size_t)row*512 + e0] = lo;
}

__global__ void p_init(const float* __restrict__ h0,
                       u16* __restrict__ hf, u16* __restrict__ of,
                       u32* __restrict__ flags){
  int idx = blockIdx.x*256 + threadIdx.x;
  if (idx < 65536){
    float hv = h0[idx];
    hf[idx] = f2h(hv);     // parity-0 buffer
    of[idx] = 0;
  } else if (idx < 65536 + 8448){
    flags[idx - 65536] = 0;   // 8192 barrier flags + 128 psum flags (+pad)
  }
}

// ---------------- enc_proj + Vu GEMM (fp32 in, f16 out): M=16384 N=2048 K=2048 ----
union SharedU {
  struct { u16 a[128*72]; u16 b[128*72]; } st;
  float cc[128*128];
};

__global__ __launch_bounds__(256) void k_gemm32(
    const float* __restrict__ A, const float* __restrict__ Bm,
    const float* __restrict__ bias, u16* __restrict__ ep, u16* __restrict__ vu)
{
  __shared__ SharedU sm;
  const int tid = threadIdx.x;
  const int lane = tid & 63, w = tid >> 6;
  const int wm = w >> 1, wn = w & 1;
  int lw = blockIdx.y * gridDim.x + blockIdx.x;       // 2048
  int swz = (lw & 7)*256 + (lw >> 3);
  const int n0 = (swz & 15) * 128, m0 = (swz >> 4) * 128;
  f32x4 acc[4][4];
#pragma unroll
  for (int i=0;i<4;i++)
#pragma unroll
    for (int j=0;j<4;j++) acc[i][j] = (f32x4)(0.f);

  for (int k0 = 0; k0 < 2048; k0 += 64) {
    __syncthreads();
#pragma unroll
    for (int i=0;i<8;i++){
      int idx = tid + i*256;
      int r = idx >> 4, c4 = idx & 15;
      float4 va = *(const float4*)(&A[(size_t)(m0+r)*2048 + k0 + c4*4]);
      ushort4 sa; sa.x=f2h(va.x); sa.y=f2h(va.y); sa.z=f2h(va.z); sa.w=f2h(va.w);
      *(ushort4*)(&sm.st.a[r*72 + c4*4]) = sa;
      float4 vb = *(const float4*)(&Bm[(size_t)(n0+r)*2048 + k0 + c4*4]);
      ushort4 sb; sb.x=f2h(vb.x); sb.y=f2h(vb.y); sb.z=f2h(vb.z); sb.w=f2h(vb.w);
      *(ushort4*)(&sm.st.b[r*72 + c4*4]) = sb;
    }
    __syncthreads();
#pragma unroll
    for (int kk = 0; kk < 64; kk += 32) {
      f16x8 af[4], bfr[4];
      int krow = kk + ((lane >> 4) << 3);
#pragma unroll
      for (int m4=0;m4<4;m4++)
        af[m4] = *(const f16x8*)(&sm.st.a[(wm*64 + m4*16 + (lane & 15))*72 + krow]);
#pragma unroll
      for (int n4=0;n4<4;n4++)
        bfr[n4] = *(const f16x8*)(&sm.st.b[(wn*64 + n4*16 + (lane & 15))*72 + krow]);
#pragma unroll
      for (int m4=0;m4<4;m4++)
#pragma unroll
        for (int n4=0;n4<4;n4++)
          acc[m4][n4] = __builtin_amdgcn_mfma_f32_16x16x32_f16(af[m4], bfr[n4], acc[m4][n4], 0,0,0);
    }
  }
  __syncthreads();
#pragma unroll
  for (int m4=0;m4<4;m4++)
#pragma unroll
    for (int n4=0;n4<4;n4++)
#pragma unroll
      for (int i=0;i<4;i++){
        int row = wm*64 + m4*16 + ((lane>>4)<<2) + i;
        int col = wn*64 + n4*16 + (lane&15);
        sm.cc[row*128 + col] = acc[m4][n4][i];
      }
  __syncthreads();
  for (int idx = tid; idx < 128*128; idx += 256) {
    int row = idx >> 7, col = idx & 127;
    int gm = m0 + row, gn = n0 + col;
    float vv = sm.cc[idx];
    if (gn < 1024) { vv += bias[gn]; ep[(size_t)gm*1024 + gn] = f2h(vv); }
    else           { vu[(size_t)gm*1024 + (gn-1024)] = f2h(vv); }
  }
}

// ---------------- gY GEMM: gY[(t*64+b)][j'] = Y[t,b,:]·WY[j',:] -> f16 ----
__global__ __launch_bounds__(256) void k_gy(
    const u16* __restrict__ Ah, const u16* __restrict__ Al,
    const u16* __restrict__ Bh, const u16* __restrict__ Bl,
    u16* __restrict__ gY)
{
  __shared__ u16 sah[128*40], sal[128*40], sbh[128*40], sbl[128*40];
  const int tid = threadIdx.x;
  const int lane = tid & 63, w = tid >> 6;
  const int wm = w >> 1, wn = w & 1;
  const int l15 = lane & 15, q8 = (lane>>4)*8;
  int lw = blockIdx.y * gridDim.x + blockIdx.x;       // 2048
  int swz = (lw & 7)*256 + (lw >> 3);
  const int n0 = (swz & 31)*128, m0 = (swz >> 5)*128;
  f32x4 acc[4][4];
#pragma unroll
  for (int i=0;i<4;i++)
#pragma unroll
    for (int j=0;j<4;j++) acc[i][j] = (f32x4)(0.f);

  for (int k0 = 0; k0 < 512; k0 += 32){
    __syncthreads();
#pragma unroll
    for (int i=0;i<8;i++){
      int idx = i*256 + tid;          // 2048 = 4 mats x 512 u16x8
      int mat = idx >> 9, sub = idx & 511;
      int r = sub >> 2, c8 = (sub & 3)*8;
      const u16* src = (mat==0)?Ah:(mat==1)?Al:(mat==2)?Bh:Bl;
      size_t base = (mat<2 ? (size_t)(m0+r)*512 : (size_t)(n0+r)*512) + k0 + c8;
      u16x8 v = *(const u16x8*)(src + base);
      u16* dst = (mat==0)?sah:(mat==1)?sal:(mat==2)?sbh:sbl;
      *(u16x8*)(&dst[r*40 + c8]) = v;
    }
    __syncthreads();
    bf16x8 ah[4], al2[4], bh[4], bl2[4];
#pragma unroll
    for (int m4=0;m4<4;m4++){
      ah[m4]  = *(const bf16x8*)(&sah[(wm*64+m4*16+l15)*40 + q8]);
      al2[m4] = *(const bf16x8*)(&sal[(wm*64+m4*16+l15)*40 + q8]);
    }
#pragma unroll
    for (int n4=0;n4<4;n4++){
      bh[n4]  = *(const bf16x8*)(&sbh[(wn*64+n4*16+l15)*40 + q8]);
      bl2[n4] = *(const bf16x8*)(&sbl[(wn*64+n4*16+l15)*40 + q8]);
    }
#pragma unroll
    for (int m4=0;m4<4;m4++)
#pragma unroll
      for (int n4=0;n4<4;n4++){
        acc[m4][n4] = __builtin_amdgcn_mfma_f32_16x16x32_bf16(ah[m4],  bh[n4],  acc[m4][n4], 0,0,0);
        acc[m4][n4] = __builtin_amdgcn_mfma_f32_16x16x32_bf16(al2[m4], bh[n4],  acc[m4][n4], 0,0,0);
        acc[m4][n4] = __builtin_amdgcn_mfma_f32_16x16x32_bf16(ah[m4],  bl2[n4], acc[m4][n4], 0,0,0);
      }
  }
#pragma unroll
  for (int m4=0;m4<4;m4++)
#pragma unroll
    for (int n4=0;n4<4;n4++)
#pragma unroll
      for (int i=0;i<4;i++){
        int gm = m0 + wm*64 + m4*16 + ((lane>>4)<<2) + i;
        int gn = n0 + wn*64 + n4*16 + l15;
        gY[(size_t)gm*4096 + gn] = f2h(acc[m4][n4][i]);
      }
}

// ---------------- persistent recurrence kernel ----------------
// P1 grid roles: blk = jg*4 + kh*2 + bh. Block owns 64 j'-rows (jg), one k-half
// (kh: 0=o-part/Wih, 1=h-part/Whh) and 32 b's (bh). Weights in LDS (128 KB).
// kh=0 writes psum+flag; kh=1 merges, adds gY, lane-local LSTM (c in regs).
struct LoopShared {
  u16 wg[64*1024];                       // 128 KB f16 weights, byte ^= ((row&7)<<4)
  union {
    struct { u16 hstage[32][16]; } p1;
    struct { float al[256]; float pared[4][256]; float red[8]; } p3;
  } u;
};

__global__ __launch_bounds__(256, 1) void k_loop(
    const float* __restrict__ Wih, const float* __restrict__ Whh,
    const float* __restrict__ c0g,
    const u16* __restrict__ Wuh16, const u16* __restrict__ gY,
    const u16* __restrict__ ep, const u16* __restrict__ vuu,
    u16* __restrict__ hf, u16* __restrict__ of,
    float* __restrict__ ebuf, float* __restrict__ phB,
    u16* __restrict__ comb, float* __restrict__ psum, u32* __restrict__ flags)
{
  __shared__ LoopShared sh;
  const int tid = threadIdx.x, blk = blockIdx.x;
  const int lane = tid & 63, w = tid >> 6;
  const int l15 = lane & 15, q = lane >> 4;
  const int jg = blk >> 2, kh = (blk >> 1) & 1, bh = blk & 1;
  u32* pflag = flags + 8192;

  // ---- one-time: 64 j'-rows of this k-half into LDS (f16, swizzled) ----
  for (int i = tid; i < 64*256; i += 256){
    int r = i >> 8, c4 = i & 255;
    int jp = jg*64 + r;
    int j  = (jp & 3)*1024 + (jp >> 2);
    float4 v = kh ? *(const float4*)(&Whh[(size_t)j*1024 + c4*4])
                  : *(const float4*)(&Wih[(size_t)j*1536 + c4*4]);
    ushort4 hh; hh.x=f2h(v.x); hh.y=f2h(v.y); hh.z=f2h(v.z); hh.w=f2h(v.w);
    int byteoff = (r*2048 + c4*8) ^ ((r & 7) << 4);
    *(ushort4*)((char*)sh.wg + byteoff) = hh;
  }
  float cReg[2] = {0.f, 0.f};
  if (kh){
#pragma unroll
    for (int bt=0;bt<2;bt++)
      cReg[bt] = c0g[(size_t)(bh*32+bt*16+l15)*1024 + jg*16 + w*4 + q];
  }
  __syncthreads();
  const char* wgc = (const char*)sh.wg;

  for (int t = 0; t < TSTEPS; ++t){
    const int p = t & 1;
    const u16* hP = hf + p*65536;
    u16* hN = hf + (p^1)*65536;

    // ======== P1: gates MFMA (A=LDS weights, B=x bypass), cross-block k-split ========
    {
      const u64* xsrc = kh ? (const u64*)hP : (const u64*)of;
      f32x4 acc[2];
      acc[0] = (f32x4)(0.f); acc[1] = (f32x4)(0.f);
#pragma unroll 4
      for (int kt=0; kt<32; ++kt){
        int wb = ((w*16+l15)*2048 + kt*64 + q*16) ^ ((l15 & 7) << 4);
        f16x8 wf = *(const f16x8*)(wgc + wb);
        const u64* px0 = xsrc + (size_t)(bh*32 + l15)*256 + kt*8 + q*2;
        f16x8 xf0 = mk8h(ldg64(px0), ldg64(px0+1));
        const u64* px1 = px0 + 16*256;
        f16x8 xf1 = mk8h(ldg64(px1), ldg64(px1+1));
        acc[0] = __builtin_amdgcn_mfma_f32_16x16x32_f16(wf, xf0, acc[0], 0,0,0);
        acc[1] = __builtin_amdgcn_mfma_f32_16x16x32_f16(wf, xf1, acc[1], 0,0,0);
      }
      if (!kh){
        float* pb = psum + ((size_t)(jg*2+bh)*32*64);
#pragma unroll
        for (int bt=0;bt<2;bt++){
          union{u64 qq[2]; float f[4];} uu;
          uu.f[0]=acc[bt][0]; uu.f[1]=acc[bt][1]; uu.f[2]=acc[bt][2]; uu.f[3]=acc[bt][3];
          u64* pp = (u64*)(pb + (bt*16+l15)*64 + w*16 + q*4);
          stg64(pp, uu.qq[0]); stg64(pp+1, uu.qq[1]);
        }
        asm volatile("s_waitcnt vmcnt(0)" ::: "memory");
        __syncthreads();
        if (tid == 0)
          __hip_atomic_store(&pflag[jg*2+bh], (u32)(t+1), __ATOMIC_RELAXED, __HIP_MEMORY_SCOPE_AGENT);
      } else {
        if (tid == 0){
          while (__hip_atomic_load(&pflag[jg*2+bh], __ATOMIC_RELAXED, __HIP_MEMORY_SCOPE_AGENT) < (u32)(t+1))
            __builtin_amdgcn_s_sleep(1);
        }
        __syncthreads();
        const float* pb = psum + ((size_t)(jg*2+bh)*32*64);
#pragma unroll
        for (int bt=0;bt<2;bt++){
          const u64* pp = (const u64*)(pb + (bt*16+l15)*64 + w*16 + q*4);
          union{u64 qq; float f[2];} u0, u1;
          u0.qq = ldg64(pp); u1.qq = ldg64(pp+1);
          int b = bh*32 + bt*16 + l15;
          const u16* gb = gY + ((size_t)(t*64 + b))*4096 + jg*64 + w*16 + q*4;
          ushort4 g0 = *(const ushort4*)gb;
          float gi = acc[bt][0] + u0.f[0] + h2f(g0.x);
          float gf = acc[bt][1] + u0.f[1] + h2f(g0.y);
          float gg = acc[bt][2] + u1.f[0] + h2f(g0.z);
          float go = acc[bt][3] + u1.f[1] + h2f(g0.w);
          gi = 1.f/(1.f+expf(-gi)); gf = 1.f/(1.f+expf(-gf));
          gg = tanhf(gg);           go = 1.f/(1.f+expf(-go));
          float cn = gf*cReg[bt] + gi*gg; cReg[bt] = cn;
          sh.u.p1.hstage[bt*16+l15][w*4+q] = f2h(go*tanhf(cn));
        }
        __syncthreads();
        if (tid < 64){
          int bloc = tid >> 1, j8 = (tid & 1)*8;
          u64 v0 = *(const u64*)&sh.u.p1.hstage[bloc][j8];
          u64 v1 = *(const u64*)&sh.u.p1.hstage[bloc][j8+4];
          u64* dst = (u64*)hN + (((size_t)(bh*32+bloc)*1024 + jg*16 + j8) >> 2);
          stg64(dst, v0); stg64(dst+1, v1);
        }
      }
    }
    gbar(flags, (u32)(t*3 + 1));

    // ======== P2: ph MFMA (blocks 0..15) | e_t (blocks 16..255) ========
    if (blk < 16){
      const int jrow = blk*64 + w*16 + l15;
      const u16* wp = Wuh16 + (size_t)jrow*1024;
      f32x4 pacc[4];
#pragma unroll
      for (int i=0;i<4;i++) pacc[i] = (f32x4)(0.f);
#pragma unroll 2
      for (int kt = 0; kt < 32; ++kt){
        f16x8 bfr = *(const f16x8*)(wp + kt*32 + q*8);
#pragma unroll
        for (int m=0;m<4;m++){
          const u64* px = (const u64*)hN + (size_t)(m*16+l15)*256 + kt*8 + q*2;
          f16x8 xf = mk8h(ldg64(px), ldg64(px+1));
          pacc[m] = __builtin_amdgcn_mfma_f32_16x16x32_f16(xf, bfr, pacc[m], 0,0,0);
        }
      }
#pragma unroll
      for (int m=0;m<4;m++)
#pragma unroll
        for (int i=0;i<4;i++){
          int bb = m*16 + q*4 + i;
          stgf(phB + (size_t)bb*1024 + jrow, pacc[m][i]);
        }
    } else {
      for (int u2 = blk - 16; u2 < 256; u2 += 240){
        const int ab = u2 >> 2, sl = u2 & 3;
        float hr[64];
        {
          const u64* hp = (const u64*)hN + (size_t)ab*256 + l15*16;
#pragma unroll
          for (int i=0;i<16;i++){
            union{u64 q_; u16 s[4];} uu; uu.q_ = ldg64(hp + i);
#pragma unroll
            for (int e=0;e<4;e++) hr[i*4+e] = h2f(uu.s[e]);
          }
        }
        const int rbase = sl*64 + w*16;
#pragma unroll
        for (int rg = 0; rg < 4; rg++){
          int s = rbase + rg*4 + q;
          const u16x8* row = (const u16x8*)(ep + ((size_t)(ab*256 + s))*1024 + l15*64);
          float a = 0.f;
#pragma unroll
          for (int j=0;j<8;j++){
            u16x8 v = row[j];
#pragma unroll
            for (int e=0;e<8;e++) a += h2f(v[e]) * hr[j*8+e];
          }
          a += __shfl_xor(a, 1); a += __shfl_xor(a, 2);
          a += __shfl_xor(a, 4); a += __shfl_xor(a, 8);
          if (l15 == 0) stgf(ebuf + ab*256 + s, a);
        }
      }
    }
    gbar(flags, (u32)(t*3 + 2));

    // ======== P3: softmax + pa + o_t (block = (ab, jq)) ========
    {
      const int ab = blk >> 2, jq = blk & 3;
      float x = ldgf(ebuf + ab*256 + tid);
      float m_ = x;
#pragma unroll
      for (int off=32; off; off>>=1) m_ = fmaxf(m_, __shfl_xor(m_, off));
      if (lane == 0) sh.u.p3.red[w] = m_;
      __syncthreads();
      m_ = fmaxf(fmaxf(sh.u.p3.red[0],sh.u.p3.red[1]), fmaxf(sh.u.p3.red[2],sh.u.p3.red[3]));
      float pv = expf(x - m_);
      float sv = pv;
#pragma unroll
      for (int off=32; off; off>>=1) sv += __shfl_xor(sv, off);
      if (lane == 0) sh.u.p3.red[4+w] = sv;
      __syncthreads();
      float tot = sh.u.p3.red[4]+sh.u.p3.red[5]+sh.u.p3.red[6]+sh.u.p3.red[7];
      sh.u.p3.al[tid] = pv / tot;
      __syncthreads();
      float a0=0.f, a1=0.f, a2=0.f, a3=0.f;
      const u16* vb = vuu + ((size_t)(ab*256) + w*64)*1024 + jq*256 + lane*4;
      for (int s2=0; s2<64; s2++){
        float aa = sh.u.p3.al[w*64 + s2];
        ushort4 v = *(const ushort4*)(vb + (size_t)s2*1024);
        a0 += aa*h2f(v.x); a1 += aa*h2f(v.y); a2 += aa*h2f(v.z); a3 += aa*h2f(v.w);
      }
      float4 o4; o4.x=a0; o4.y=a1; o4.z=a2; o4.w=a3;
      *(float4*)(&sh.u.p3.pared[w][lane*4]) = o4;
      __syncthreads();
      if (tid < 64){
        const int col = tid*4;
        union{u64 q_; u16 s[4];} uo;
        ushort4 cw;
#pragma unroll
        for (int i=0;i<4;i++){
          float pa = sh.u.p3.pared[0][col+i] + sh.u.p3.pared[1][col+i]
                   + sh.u.p3.pared[2][col+i] + sh.u.p3.pared[3][col+i];
          pa += ldgf(phB + (size_t)ab*1024 + jq*256 + col + i);
          u16 ob = f2h(tanhf(pa));
          uo.s[i] = ob; (&cw.x)[i] = ob;
        }
        stg64((u64*)of + (size_t)ab*256 + jq*64 + tid, uo.q_);
        *(ushort4*)(comb + (size_t)(t*64 + ab)*1024 + jq*256 + col) = cw;
      }
    }
    gbar(flags, (u32)(t*3 + 3));
  }
}

// ---------------- vocab GEMM (comb f16, Wv fp32 converted in-loader) ----------------
__global__ __launch_bounds__(256) void k_gemm16(
    const u16* __restrict__ A, const float* __restrict__ Bm,
    const float* __restrict__ bias,
    float* __restrict__ pm, float* __restrict__ ps,
    float* __restrict__ gl, const int* __restrict__ ids)
{
  __shared__ SharedU sm;
  const int tid = threadIdx.x;
  const int lane = tid & 63, w = tid >> 6;
  const int wm = w >> 1, wn = w & 1;
  int lw = blockIdx.y * 250 + blockIdx.x;        // 16000
  int swz = (lw & 7)*2000 + (lw >> 3);
  const int n0 = (swz % 250) * 128, m0 = (swz / 250) * 128;
  f32x4 acc[4][4];
#pragma unroll
  for (int i=0;i<4;i++)
#pragma unroll
    for (int j=0;j<4;j++) acc[i][j] = (f32x4)(0.f);

  for (int k0 = 0; k0 < 1024; k0 += 64) {
    __syncthreads();
#pragma unroll
    for (int i=0;i<8;i++){
      int idx = i*256 + tid;
      int half = idx >> 10, id2 = idx & 1023;
      int r = id2 >> 3, c8 = (id2 & 7)*8;
      if (half == 0){
        int gm = m0 + r;
        u16x8 v = {0,0,0,0,0,0,0,0};
        if (gm < MROWS) v = *(const u16x8*)(A + (size_t)gm*1024 + k0 + c8);
        *(u16x8*)(&sm.st.a[r*72 + c8]) = v;
      } else {
        const float* src = Bm + (size_t)(n0 + r)*1024 + k0 + c8;
        float4 a4 = *(const float4*)src;
        float4 b4 = *(const float4*)(src + 4);
        ushort4 ha; ha.x=f2h(a4.x); ha.y=f2h(a4.y); ha.z=f2h(a4.z); ha.w=f2h(a4.w);
        ushort4 hb; hb.x=f2h(b4.x); hb.y=f2h(b4.y); hb.z=f2h(b4.z); hb.w=f2h(b4.w);
        *(ushort4*)(&sm.st.b[r*72 + c8]) = ha;
        *(ushort4*)(&sm.st.b[r*72 + c8 + 4]) = hb;
      }
    }
    __syncthreads();
#pragma unroll
    for (int kk = 0; kk < 64; kk += 32) {
      f16x8 af[4], bfr[4];
      int krow = kk + ((lane >> 4) << 3);
#pragma unroll
      for (int m4=0;m4<4;m4++)
        af[m4] = *(const f16x8*)(&sm.st.a[(wm*64 + m4*16 + (lane & 15))*72 + krow]);
#pragma unroll
      for (int n4=0;n4<4;n4++)
        bfr[n4] = *(const f16x8*)(&sm.st.b[(wn*64 + n4*16 + (lane & 15))*72 + krow]);
#pragma unroll
      for (int m4=0;m4<4;m4++)
#pragma unroll
        for (int n4=0;n4<4;n4++)
          acc[m4][n4] = __builtin_amdgcn_mfma_f32_16x16x32_f16(af[m4], bfr[n4], acc[m4][n4], 0,0,0);
    }
  }
  __syncthreads();
#pragma unroll
  for (int m4=0;m4<4;m4++)
#pragma unroll
    for (int n4=0;n4<4;n4++)
#pragma unroll
      for (int i=0;i<4;i++){
        int row = wm*64 + m4*16 + ((lane>>4)<<2) + i;
        int col = wn*64 + n4*16 + (lane&15);
        sm.cc[row*128 + col] = acc[m4][n4][i];
      }
  __syncthreads();

  if (tid < 128) {
    int row = tid, gm = m0 + row;
    if (gm < MROWS) {
      float mx = -1e30f;
      for (int j=0;j<128;j++){
        int col = (row + j) & 127;
        float x = sm.cc[row*128+col] + bias[n0+col];
        mx = fmaxf(mx, x);
      }
      float sum = 0.f;
      for (int j=0;j<128;j++){
        int col = (row + j) & 127;
        float x = sm.cc[row*128+col] + bias[n0+col];
        sum += expf(x - mx);
      }
      pm[(size_t)gm*NVB + n0/128] = mx;
      ps[(size_t)gm*NVB + n0/128] = sum;
      int g = ids[gm + 64];
      unsigned d = (unsigned)(g - n0);
      if (d < 128u) gl[gm] = sm.cc[row*128 + (int)d] + bias[g];
    }
  }
}

// ---------------- final reduce ----------------
__global__ void k_reduce(const float* __restrict__ pm, const float* __restrict__ ps,
                         const float* __restrict__ gl, const int* __restrict__ ids,
                         float* __restrict__ out)
{
  int b = blockIdx.x, tid = threadIdx.x;
  int lane = tid & 63, w = tid >> 6;
  __shared__ float wacc[4];
  float accum = 0.f;
  for (int t = w; t < TSTEPS; t += 4) {
    int r = t*64 + b;
    const float* pmr = pm + (size_t)r*NVB;
    const float* psr = ps + (size_t)r*NVB;
    float mx = -1e30f;
    for (int p2 = lane; p2 < NVB; p2 += 64) mx = fmaxf(mx, pmr[p2]);
#pragma unroll
    for (int off=32; off; off>>=1) mx = fmaxf(mx, __shfl_xor(mx, off));
    float sm = 0.f;
    for (int p2 = lane; p2 < NVB; p2 += 64) sm += psr[p2] * expf(pmr[p2] - mx);
#pragma unroll
    for (int off=32; off; off>>=1) sm += __shfl_xor(sm, off);
    if (lane == 0) {
      int g = ids[r + 64];
      if (g != 0) accum += gl[r] - (mx + logf(sm));
    }
  }
  if (lane == 0) wacc[w] = accum;
  __syncthreads();
  if (tid == 0) out[b] = wacc[0]+wacc[1]+wacc[2]+wacc[3];
}

// ---------------- host ----------------
extern "C" void kernel_launch(void* const* d_in, const int* in_sizes, int n_in,
                              void* d_out, int out_size, void* d_ws, size_t ws_size,
                              hipStream_t stream)
{
  const int*   ids  = (const int*)d_in[0];
  const float* vc   = (const float*)d_in[1];
  const float* h0   = (const float*)d_in[2];
  const float* c0   = (const float*)d_in[3];
  const float* Etgt = (const float*)d_in[4];
  const float* Watt = (const float*)d_in[5];
  const float* batt = (const float*)d_in[6];
  const float* Wih  = (const float*)d_in[7];
  const float* Whh  = (const float*)d_in[8];
  const float* Wu   = (const float*)d_in[9];
  const float* Wv   = (const float*)d_in[10];
  const float* bv   = (const float*)d_in[11];
  float* out = (float*)d_out;

  char* p = (char*)d_ws;
  auto alloc = [&](size_t bytes)->char* {
    char* r = p; p += (bytes + 255) & ~(size_t)255; return r;
  };
  u32* flags = (u32*)alloc(36864);               // 8192 barrier + 128 psum flags
  u16* Yh    = (u16*)alloc((size_t)8192*512*2);
  u16* Yl    = (u16*)alloc((size_t)8192*512*2);
  u16* WYh   = (u16*)alloc((size_t)4096*512*2);
  u16* WYl   = (u16*)alloc((size_t)4096*512*2);
  u16* Wuh16 = (u16*)alloc((size_t)1024*1024*2);
  float* Wcat= (float*)alloc((size_t)2048*2048*4);
  u16* ep    = (u16*)alloc((size_t)64*256*1024*2);
  u16* vuu   = (u16*)alloc((size_t)64*256*1024*2);
  u16* comb  = (u16*)alloc((size_t)8192*1024*2);
  u16* gY    = (u16*)alloc((size_t)8192*4096*2);
  u16* hfbuf = (u16*)alloc((size_t)2*65536*2);
  u16* ofbuf = (u16*)alloc(65536*2);
  float* ebuf= (float*)alloc((size_t)64*256*4);
  float* phB = (float*)alloc((size_t)64*1024*4);
  float* psum= (float*)alloc((size_t)128*32*64*4);   // 1 MB
  float* pm  = (float*)alloc((size_t)MROWS*NVB*4);
  float* ps  = (float*)alloc((size_t)MROWS*NVB*4);
  float* gl  = (float*)alloc((size_t)MROWS*4);

  p_init<<<289, 256, 0, stream>>>(h0, hfbuf, ofbuf, flags);
  p_wcat<<<(2048*2048)/256, 256, 0, stream>>>(Watt, Wu, Wcat);
  p_wy<<<dim3(2, 4096), 256, 0, stream>>>(Wih, WYh, WYl);
  p_wuh<<<dim3(4, 1024), 256, 0, stream>>>(Wu, Wuh16);
  p_y<<<dim3(2, 8192), 256, 0, stream>>>(ids, Etgt, Yh, Yl);

  k_gemm32<<<dim3(16, 128), 256, 0, stream>>>(vc, Wcat, batt, ep, vuu);
  k_gy<<<dim3(32, 64), 256, 0, stream>>>(Yh, Yl, WYh, WYl, gY);

  k_loop<<<NBLK, 256, 0, stream>>>(Wih, Whh, c0, Wuh16, gY, ep, vuu,
                                   hfbuf, ofbuf, ebuf, phB, comb, psum, flags);

  k_gemm16<<<dim3(NVB, 64), 256, 0, stream>>>(comb, Wv, bv, pm, ps, gl, ids);
  k_reduce<<<64, 256, 0, stream>>>(pm, ps, gl, ids, out);
}

// Round 11
// 12969.188 us; speedup vs baseline: 1.1670x; 1.1087x over previous
//
#include <hip/hip_runtime.h>
#include <hip/hip_bf16.h>

#define TSTEPS 127
#define NBLK 256
#define NVB 250      // 32000/128
#define MROWS 8128   // 127*64

typedef unsigned short u16;
typedef unsigned int u32;
typedef unsigned long long u64;
typedef unsigned char u8;
typedef _Float16 f16;
typedef __attribute__((ext_vector_type(8))) short bf16x8;
typedef __attribute__((ext_vector_type(8))) _Float16 f16x8;
typedef __attribute__((ext_vector_type(8))) unsigned short u16x8;
typedef __attribute__((ext_vector_type(4))) float f32x4;
typedef __attribute__((ext_vector_type(2))) float f32x2;

__device__ __forceinline__ u16 f2h(float f){ f16 h=(f16)f; u16 r; __builtin_memcpy(&r,&h,2); return r; }
__device__ __forceinline__ float h2f(u16 u){ f16 h; __builtin_memcpy(&h,&u,2); return (float)h; }
__device__ __forceinline__ float us2f(u16 u){ union{float f;u32 i;}v; v.i=(u32)u<<16; return v.f; }
__device__ __forceinline__ u16 f2us(float f){ __hip_bfloat16 h=__float2bfloat16(f); u16 r; __builtin_memcpy(&r,&h,2); return r; }
__device__ __forceinline__ void split2(float x, u16& hi, u16& lo){
  u16 h = f2us(x); lo = f2us(x - us2f(h)); hi = h;
}

// ---- agent-scope relaxed atomics for mutable shared state ----
__device__ __forceinline__ u64 ldg64(const u64* p){
  return __hip_atomic_load((u64*)p, __ATOMIC_RELAXED, __HIP_MEMORY_SCOPE_AGENT);
}
__device__ __forceinline__ float ldgf(const float* p){
  return __hip_atomic_load((float*)p, __ATOMIC_RELAXED, __HIP_MEMORY_SCOPE_AGENT);
}
__device__ __forceinline__ void stg64(u64* p, u64 v){
  __hip_atomic_store(p, v, __ATOMIC_RELAXED, __HIP_MEMORY_SCOPE_AGENT);
}
__device__ __forceinline__ void stg32(u32* p, u32 v){
  __hip_atomic_store(p, v, __ATOMIC_RELAXED, __HIP_MEMORY_SCOPE_AGENT);
}
__device__ __forceinline__ void stgf(float* p, float v){
  __hip_atomic_store(p, v, __ATOMIC_RELAXED, __HIP_MEMORY_SCOPE_AGENT);
}
__device__ __forceinline__ f16x8 mk8h(u64 a, u64 b){
  union { u64 q[2]; f16x8 v; } u; u.q[0]=a; u.q[1]=b; return u.v;
}

// flag-array barrier: only wave 0 spins (lane l watches 4 flags), no invalidate
__device__ __forceinline__ void gbar(u32* flags, u32 token){
  asm volatile("s_waitcnt vmcnt(0) lgkmcnt(0)" ::: "memory");
  __syncthreads();
  if (threadIdx.x == 0)
    __hip_atomic_store(&flags[blockIdx.x*32], token, __ATOMIC_RELAXED, __HIP_MEMORY_SCOPE_AGENT);
  if (threadIdx.x < 64){
    const int l = threadIdx.x;
    for (;;){
      bool ok = true;
#pragma unroll
      for (int i=0;i<4;i++)
        ok &= (__hip_atomic_load(&flags[(l*4+i)*32], __ATOMIC_RELAXED, __HIP_MEMORY_SCOPE_AGENT) >= token);
      if (__all(ok)) break;
      __builtin_amdgcn_s_sleep(8);
    }
  }
  __syncthreads();
}

// ---------------- prep kernels ----------------
__global__ void p_wcat(const float* __restrict__ Watt, const float* __restrict__ Wu,
                       float* __restrict__ Wcat){
  int idx = blockIdx.x*256 + threadIdx.x;      // 2048*2048
  int n = idx >> 11, k = idx & 2047;
  Wcat[idx] = (n < 1024) ? Watt[idx] : Wu[(size_t)(n-1024)*3072 + k];
}

// WY: Y-part of Wih in j'-order (j' = jj*4+g, j = g*1024+jj), split hi/lo (for k_gy)
__global__ void p_wy(const float* __restrict__ Wih, u16* __restrict__ WYh, u16* __restrict__ WYl){
  int k = blockIdx.x*256 + threadIdx.x;        // 512
  int rp = blockIdx.y;                         // 4096
  int j = (rp & 3)*1024 + (rp >> 2);
  float v = Wih[(size_t)j*1536 + 1024 + k];
  u16 hi, lo; split2(v, hi, lo);
  WYh[(size_t)rp*512 + k] = hi; WYl[(size_t)rp*512 + k] = lo;
}

__global__ void p_wuh(const float* __restrict__ Wu, u16* __restrict__ Wh){
  int k = blockIdx.x*256 + threadIdx.x;        // 1024
  int j = blockIdx.y;                          // 1024
  Wh[(size_t)j*1024 + k] = f2h(Wu[(size_t)j*3072 + 2048 + k]);
}

__global__ void p_y(const int* __restrict__ ids, const float* __restrict__ Etgt,
                    u16* __restrict__ Yh, u16* __restrict__ Yl){
  int e0 = blockIdx.x*256 + threadIdx.x;       // 512
  int row = blockIdx.y;                        // 8192
  int id = ids[row];
  float v = Etgt[(size_t)id*512 + e0];
  u16 hi, lo; split2(v, hi, lo);
  Yh[(size_t)row*512 + e0] = hi; Yl[(size_t)row*512 + e0] = lo;
}

__global__ void p_init(const float* __restrict__ h0,
                       u16* __restrict__ hf, u16* __restrict__ of,
                       u32* __restrict__ flags){
  int idx = blockIdx.x*256 + threadIdx.x;
  if (idx < 65536){
    float hv = h0[idx];
    hf[idx] = f2h(hv);     // parity-0 buffer
    of[idx] = 0;
  } else if (idx < 65536 + 8192){
    flags[idx - 65536] = 0;
  }
}

// ---------------- enc_proj + Vu GEMM (fp32 in, FP8 out): M=16384 N=2048 K=2048 ----
union SharedU {
  struct { u16 a[128*72]; u16 b[128*72]; } st;
  float cc[128*128];
};

__global__ __launch_bounds__(256) void k_gemm32(
    const float* __restrict__ A, const float* __restrict__ Bm,
    const float* __restrict__ bias, u8* __restrict__ ep, u8* __restrict__ vu)
{
  __shared__ SharedU sm;
  const int tid = threadIdx.x;
  const int lane = tid & 63, w = tid >> 6;
  const int wm = w >> 1, wn = w & 1;
  int lw = blockIdx.y * gridDim.x + blockIdx.x;       // 2048
  int swz = (lw & 7)*256 + (lw >> 3);
  const int n0 = (swz & 15) * 128, m0 = (swz >> 4) * 128;
  f32x4 acc[4][4];
#pragma unroll
  for (int i=0;i<4;i++)
#pragma unroll
    for (int j=0;j<4;j++) acc[i][j] = (f32x4)(0.f);

  for (int k0 = 0; k0 < 2048; k0 += 64) {
    __syncthreads();
#pragma unroll
    for (int i=0;i<8;i++){
      int idx = tid + i*256;
      int r = idx >> 4, c4 = idx & 15;
      float4 va = *(const float4*)(&A[(size_t)(m0+r)*2048 + k0 + c4*4]);
      ushort4 sa; sa.x=f2h(va.x); sa.y=f2h(va.y); sa.z=f2h(va.z); sa.w=f2h(va.w);
      *(ushort4*)(&sm.st.a[r*72 + c4*4]) = sa;
      float4 vb = *(const float4*)(&Bm[(size_t)(n0+r)*2048 + k0 + c4*4]);
      ushort4 sb; sb.x=f2h(vb.x); sb.y=f2h(vb.y); sb.z=f2h(vb.z); sb.w=f2h(vb.w);
      *(ushort4*)(&sm.st.b[r*72 + c4*4]) = sb;
    }
    __syncthreads();
#pragma unroll
    for (int kk = 0; kk < 64; kk += 32) {
      f16x8 af[4], bfr[4];
      int krow = kk + ((lane >> 4) << 3);
#pragma unroll
      for (int m4=0;m4<4;m4++)
        af[m4] = *(const f16x8*)(&sm.st.a[(wm*64 + m4*16 + (lane & 15))*72 + krow]);
#pragma unroll
      for (int n4=0;n4<4;n4++)
        bfr[n4] = *(const f16x8*)(&sm.st.b[(wn*64 + n4*16 + (lane & 15))*72 + krow]);
#pragma unroll
      for (int m4=0;m4<4;m4++)
#pragma unroll
        for (int n4=0;n4<4;n4++)
          acc[m4][n4] = __builtin_amdgcn_mfma_f32_16x16x32_f16(af[m4], bfr[n4], acc[m4][n4], 0,0,0);
    }
  }
  __syncthreads();
#pragma unroll
  for (int m4=0;m4<4;m4++)
#pragma unroll
    for (int n4=0;n4<4;n4++)
#pragma unroll
      for (int i=0;i<4;i++){
        int row = wm*64 + m4*16 + ((lane>>4)<<2) + i;
        int col = wn*64 + n4*16 + (lane&15);
        sm.cc[row*128 + col] = acc[m4][n4][i];
      }
  __syncthreads();
  for (int idx = tid*2; idx < 128*128; idx += 512) {
    int row = idx >> 7, col = idx & 127;
    int gm = m0 + row, gn = n0 + col;
    float v0 = sm.cc[idx], v1 = sm.cc[idx+1];
    if (gn < 1024) {
      v0 += bias[gn]; v1 += bias[gn+1];
      int pk = __builtin_amdgcn_cvt_pk_fp8_f32(v0, v1, 0, false);
      *(u16*)(ep + (size_t)gm*1024 + gn) = (u16)(pk & 0xffff);
    } else {
      int pk = __builtin_amdgcn_cvt_pk_fp8_f32(v0, v1, 0, false);
      *(u16*)(vu + (size_t)gm*1024 + (gn-1024)) = (u16)(pk & 0xffff);
    }
  }
}

// ---------------- gY GEMM: gY[(t*64+b)][j'] = Y[t,b,:]·WY[j',:] -> f16 ----
__global__ __launch_bounds__(256) void k_gy(
    const u16* __restrict__ Ah, const u16* __restrict__ Al,
    const u16* __restrict__ Bh, const u16* __restrict__ Bl,
    u16* __restrict__ gY)
{
  __shared__ u16 sah[128*40], sal[128*40], sbh[128*40], sbl[128*40];
  const int tid = threadIdx.x;
  const int lane = tid & 63, w = tid >> 6;
  const int wm = w >> 1, wn = w & 1;
  const int l15 = lane & 15, q8 = (lane>>4)*8;
  int lw = blockIdx.y * gridDim.x + blockIdx.x;       // 2048
  int swz = (lw & 7)*256 + (lw >> 3);
  const int n0 = (swz & 31)*128, m0 = (swz >> 5)*128;
  f32x4 acc[4][4];
#pragma unroll
  for (int i=0;i<4;i++)
#pragma unroll
    for (int j=0;j<4;j++) acc[i][j] = (f32x4)(0.f);

  for (int k0 = 0; k0 < 512; k0 += 32){
    __syncthreads();
#pragma unroll
    for (int i=0;i<8;i++){
      int idx = i*256 + tid;          // 2048 = 4 mats x 512 u16x8
      int mat = idx >> 9, sub = idx & 511;
      int r = sub >> 2, c8 = (sub & 3)*8;
      const u16* src = (mat==0)?Ah:(mat==1)?Al:(mat==2)?Bh:Bl;
      size_t base = (mat<2 ? (size_t)(m0+r)*512 : (size_t)(n0+r)*512) + k0 + c8;
      u16x8 v = *(const u16x8*)(src + base);
      u16* dst = (mat==0)?sah:(mat==1)?sal:(mat==2)?sbh:sbl;
      *(u16x8*)(&dst[r*40 + c8]) = v;
    }
    __syncthreads();
    bf16x8 ah[4], al2[4], bh[4], bl2[4];
#pragma unroll
    for (int m4=0;m4<4;m4++){
      ah[m4]  = *(const bf16x8*)(&sah[(wm*64+m4*16+l15)*40 + q8]);
      al2[m4] = *(const bf16x8*)(&sal[(wm*64+m4*16+l15)*40 + q8]);
    }
#pragma unroll
    for (int n4=0;n4<4;n4++){
      bh[n4]  = *(const bf16x8*)(&sbh[(wn*64+n4*16+l15)*40 + q8]);
      bl2[n4] = *(const bf16x8*)(&sbl[(wn*64+n4*16+l15)*40 + q8]);
    }
#pragma unroll
    for (int m4=0;m4<4;m4++)
#pragma unroll
      for (int n4=0;n4<4;n4++){
        acc[m4][n4] = __builtin_amdgcn_mfma_f32_16x16x32_bf16(ah[m4],  bh[n4],  acc[m4][n4], 0,0,0);
        acc[m4][n4] = __builtin_amdgcn_mfma_f32_16x16x32_bf16(al2[m4], bh[n4],  acc[m4][n4], 0,0,0);
        acc[m4][n4] = __builtin_amdgcn_mfma_f32_16x16x32_bf16(ah[m4],  bl2[n4], acc[m4][n4], 0,0,0);
      }
  }
#pragma unroll
  for (int m4=0;m4<4;m4++)
#pragma unroll
    for (int n4=0;n4<4;n4++)
#pragma unroll
      for (int i=0;i<4;i++){
        int gm = m0 + wm*64 + m4*16 + ((lane>>4)<<2) + i;
        int gn = n0 + wn*64 + n4*16 + l15;
        gY[(size_t)gm*4096 + gn] = f2h(acc[m4][n4][i]);
      }
}

// ---------------- persistent recurrence kernel (r8 structure, fp8 streams) ----------------
struct LoopShared {
  u16 wg[32*2048];                       // f16 weights, byte ^= ((row&7)<<4)
  union {
    struct { float psum[2][64][8]; u32 hstage[32][4]; } p1;
    struct { float al[256]; float pared[4][256]; float red[8]; } p3;
  } u;
};

__global__ __launch_bounds__(256, 1) void k_loop(
    const float* __restrict__ Wih, const float* __restrict__ Whh,
    const float* __restrict__ c0g,
    const u16* __restrict__ Wuh16, const u16* __restrict__ gY,
    const u8* __restrict__ ep, const u8* __restrict__ vuu,
    u16* __restrict__ hf, u16* __restrict__ of,
    float* __restrict__ ebuf, float* __restrict__ phB,
    u16* __restrict__ comb, u32* __restrict__ flags)
{
  __shared__ LoopShared sh;
  const int tid = threadIdx.x, blk = blockIdx.x;
  const int lane = tid & 63, w = tid >> 6;
  const int l15 = lane & 15, q = lane >> 4;
  const int jb = blk >> 1, bhalf = blk & 1;
  const int bsub = w & 1, khalf = w >> 1;
  const int b = bhalf*32 + bsub*16 + l15;

  // one-time: 32 j'-rows of [Wih_o | Whh] as f16 into LDS
  for (int i = tid; i < 32*512; i += 256){
    int r = i >> 9, c4 = i & 511;
    int jp = jb*32 + r;
    int j  = (jp & 3)*1024 + (jp >> 2);
    float4 v = (c4 < 256) ? *(const float4*)(&Wih[(size_t)j*1536 + c4*4])
                          : *(const float4*)(&Whh[(size_t)j*1024 + (c4-256)*4]);
    ushort4 hh; hh.x=f2h(v.x); hh.y=f2h(v.y); hh.z=f2h(v.z); hh.w=f2h(v.w);
    int byteoff = (r*4096 + c4*8) ^ ((r & 7) << 4);
    *(ushort4*)((char*)sh.wg + byteoff) = hh;
  }
  float cReg0 = 0.f, cReg1 = 0.f;
  if (w < 2){
    cReg0 = c0g[(size_t)b*1024 + jb*8 + q];
    cReg1 = c0g[(size_t)b*1024 + jb*8 + 4 + q];
  }
  __syncthreads();
  const char* wgc = (const char*)sh.wg;

  for (int t = 0; t < TSTEPS; ++t){
    const int p = t & 1;
    const u16* hP = hf + p*65536;
    u16* hN = hf + (p^1)*65536;

    // ======== P1: gates MFMA (f16, LDS weights) + LSTM ========
    {
      float gy0[4], gy1[4];
      if (w < 2){
        const u16* gb = gY + ((size_t)(t*64 + b))*4096 + jb*32 + q*4;
        ushort4 g0 = *(const ushort4*)(gb);
        ushort4 g1 = *(const ushort4*)(gb + 16);
        gy0[0]=h2f(g0.x); gy0[1]=h2f(g0.y); gy0[2]=h2f(g0.z); gy0[3]=h2f(g0.w);
        gy1[0]=h2f(g1.x); gy1[1]=h2f(g1.y); gy1[2]=h2f(g1.z); gy1[3]=h2f(g1.w);
      }
      const u64* xsrc = (khalf ? (const u64*)hP : (const u64*)of) + b*256;
      f32x4 acc0 = (f32x4)(0.f), acc1 = (f32x4)(0.f);
#pragma unroll 4
      for (int kt = 0; kt < 32; ++kt){
        int base = khalf*2048 + kt*64 + q*16;
        int w0 = (l15*4096 + base) ^ ((l15 & 7) << 4);
        f16x8 wf0 = *(const f16x8*)(wgc + w0);
        f16x8 wf1 = *(const f16x8*)(wgc + w0 + 65536);   // row+16, same (row&7)
        const u64* px = xsrc + kt*8 + q*2;
        f16x8 xf = mk8h(ldg64(px), ldg64(px+1));
        acc0 = __builtin_amdgcn_mfma_f32_16x16x32_f16(wf0, xf, acc0, 0,0,0);
        acc1 = __builtin_amdgcn_mfma_f32_16x16x32_f16(wf1, xf, acc1, 0,0,0);
      }
      if (w >= 2){
        float* ps_ = &sh.u.p1.psum[w-2][lane][0];
#pragma unroll
        for (int i=0;i<4;i++){ ps_[i] = acc0[i]; ps_[4+i] = acc1[i]; }
      }
      __syncthreads();
      if (w < 2){
        const float* ps_ = &sh.u.p1.psum[w][lane][0];
        u16 h0b, h1b;
        {
          float gi = acc0[0]+ps_[0]+gy0[0], gf = acc0[1]+ps_[1]+gy0[1];
          float gg = acc0[2]+ps_[2]+gy0[2], go = acc0[3]+ps_[3]+gy0[3];
          gi = 1.f/(1.f+expf(-gi)); gf = 1.f/(1.f+expf(-gf));
          gg = tanhf(gg);           go = 1.f/(1.f+expf(-go));
          float cn = gf*cReg0 + gi*gg; cReg0 = cn;
          h0b = f2h(go*tanhf(cn));
        }
        {
          float gi = acc1[0]+ps_[4]+gy1[0], gf = acc1[1]+ps_[5]+gy1[1];
          float gg = acc1[2]+ps_[6]+gy1[2], go = acc1[3]+ps_[7]+gy1[3];
          gi = 1.f/(1.f+expf(-gi)); gf = 1.f/(1.f+expf(-gf));
          gg = tanhf(gg);           go = 1.f/(1.f+expf(-go));
          float cn = gf*cReg1 + gi*gg; cReg1 = cn;
          h1b = f2h(go*tanhf(cn));
        }
        int bl = bsub*16 + l15;
        u16* hs = (u16*)sh.u.p1.hstage;
        hs[bl*8 + q] = h0b;
        hs[bl*8 + 4 + q] = h1b;
      }
      __syncthreads();
      if (tid < 128){
        int bl = tid >> 2, sub = tid & 3;
        u32 v = sh.u.p1.hstage[bl][sub];
        stg32((u32*)hN + (size_t)(bhalf*32 + bl)*512 + jb*4 + sub, v);
      }
    }
    gbar(flags, (u32)(t*3 + 1));

    // ======== P2: ph MFMA (blocks 0..15) | e_t fp8 (blocks 16..255) ========
    if (blk < 16){
      const int jrow = blk*64 + w*16 + l15;
      const u16* wp = Wuh16 + (size_t)jrow*1024;
      f32x4 pacc[4];
#pragma unroll
      for (int i=0;i<4;i++) pacc[i] = (f32x4)(0.f);
#pragma unroll 2
      for (int kt = 0; kt < 32; ++kt){
        f16x8 bfr = *(const f16x8*)(wp + kt*32 + q*8);
#pragma unroll
        for (int m=0;m<4;m++){
          const u64* px = (const u64*)hN + (size_t)(m*16+l15)*256 + kt*8 + q*2;
          f16x8 xf = mk8h(ldg64(px), ldg64(px+1));
          pacc[m] = __builtin_amdgcn_mfma_f32_16x16x32_f16(xf, bfr, pacc[m], 0,0,0);
        }
      }
#pragma unroll
      for (int m=0;m<4;m++)
#pragma unroll
        for (int i=0;i<4;i++){
          int bb = m*16 + q*4 + i;
          stgf(phB + (size_t)bb*1024 + jrow, pacc[m][i]);
        }
    } else {
      for (int u2 = blk - 16; u2 < 256; u2 += 240){
        const int ab = u2 >> 2, sl = u2 & 3;
        // per-lane h slice k = l15*64 .. +64 (f16)
        float hr[64];
        {
          const u64* hp = (const u64*)hN + (size_t)ab*256 + l15*16;
#pragma unroll
          for (int i=0;i<16;i++){
            union{u64 q_; u16 s[4];} uu; uu.q_ = ldg64(hp + i);
#pragma unroll
            for (int e=0;e<4;e++) hr[i*4+e] = h2f(uu.s[e]);
          }
        }
        const int rbase = sl*64 + w*16;
#pragma unroll
        for (int rg = 0; rg < 4; rg++){
          int s = rbase + rg*4 + q;
          const uint4* row = (const uint4*)(ep + ((size_t)(ab*256 + s))*1024 + l15*64);
          float a = 0.f;
#pragma unroll
          for (int c=0;c<4;c++){
            uint4 v = row[c];
#pragma unroll
            for (int e=0;e<4;e++){
              u32 wv = (&v.x)[e];
              f32x2 lo = __builtin_amdgcn_cvt_pk_f32_fp8(wv, false);
              f32x2 hi = __builtin_amdgcn_cvt_pk_f32_fp8(wv, true);
              int bse = c*16 + e*4;
              a += lo.x*hr[bse] + lo.y*hr[bse+1] + hi.x*hr[bse+2] + hi.y*hr[bse+3];
            }
          }
          a += __shfl_xor(a, 1); a += __shfl_xor(a, 2);
          a += __shfl_xor(a, 4); a += __shfl_xor(a, 8);
          if (l15 == 0) stgf(ebuf + ab*256 + s, a);
        }
      }
    }
    gbar(flags, (u32)(t*3 + 2));

    // ======== P3: softmax + pa (fp8 vuu) + o_t ========
    {
      const int ab = blk >> 2, jq = blk & 3;
      float x = ldgf(ebuf + ab*256 + tid);
      float m_ = x;
#pragma unroll
      for (int off=32; off; off>>=1) m_ = fmaxf(m_, __shfl_xor(m_, off));
      if (lane == 0) sh.u.p3.red[w] = m_;
      __syncthreads();
      m_ = fmaxf(fmaxf(sh.u.p3.red[0],sh.u.p3.red[1]), fmaxf(sh.u.p3.red[2],sh.u.p3.red[3]));
      float pv = expf(x - m_);
      float sv = pv;
#pragma unroll
      for (int off=32; off; off>>=1) sv += __shfl_xor(sv, off);
      if (lane == 0) sh.u.p3.red[4+w] = sv;
      __syncthreads();
      float tot = sh.u.p3.red[4]+sh.u.p3.red[5]+sh.u.p3.red[6]+sh.u.p3.red[7];
      sh.u.p3.al[tid] = pv / tot;
      __syncthreads();
      float a0=0.f, a1=0.f, a2=0.f, a3=0.f;
      const u8* vb = vuu + ((size_t)(ab*256) + w*64)*1024 + jq*256 + lane*4;
      for (int s2=0; s2<64; s2++){
        float aa = sh.u.p3.al[w*64 + s2];
        u32 v = *(const u32*)(vb + (size_t)s2*1024);
        f32x2 lo = __builtin_amdgcn_cvt_pk_f32_fp8(v, false);
        f32x2 hi = __builtin_amdgcn_cvt_pk_f32_fp8(v, true);
        a0 += aa*lo.x; a1 += aa*lo.y; a2 += aa*hi.x; a3 += aa*hi.y;
      }
      float4 o4; o4.x=a0; o4.y=a1; o4.z=a2; o4.w=a3;
      *(float4*)(&sh.u.p3.pared[w][lane*4]) = o4;
      __syncthreads();
      if (tid < 64){
        const int col = tid*4;
        union{u64 q_; u16 s[4];} uo;
        ushort4 cw;
#pragma unroll
        for (int i=0;i<4;i++){
          float pa = sh.u.p3.pared[0][col+i] + sh.u.p3.pared[1][col+i]
                   + sh.u.p3.pared[2][col+i] + sh.u.p3.pared[3][col+i];
          pa += ldgf(phB + (size_t)ab*1024 + jq*256 + col + i);
          u16 ob = f2h(tanhf(pa));
          uo.s[i] = ob; (&cw.x)[i] = ob;
        }
        stg64((u64*)of + (size_t)ab*256 + jq*64 + tid, uo.q_);
        *(ushort4*)(comb + (size_t)(t*64 + ab)*1024 + jq*256 + col) = cw;
      }
    }
    gbar(flags, (u32)(t*3 + 3));
  }
}

// ---------------- vocab GEMM (comb f16, Wv fp32 converted in-loader) ----------------
__global__ __launch_bounds__(256) void k_gemm16(
    const u16* __restrict__ A, const float* __restrict__ Bm,
    const float* __restrict__ bias,
    float* __restrict__ pm, float* __restrict__ ps,
    float* __restrict__ gl, const int* __restrict__ ids)
{
  __shared__ SharedU sm;
  const int tid = threadIdx.x;
  const int lane = tid & 63, w = tid >> 6;
  const int wm = w >> 1, wn = w & 1;
  int lw = blockIdx.y * 250 + blockIdx.x;        // 16000
  int swz = (lw & 7)*2000 + (lw >> 3);
  const int n0 = (swz % 250) * 128, m0 = (swz / 250) * 128;
  f32x4 acc[4][4];
#pragma unroll
  for (int i=0;i<4;i++)
#pragma unroll
    for (int j=0;j<4;j++) acc[i][j] = (f32x4)(0.f);

  for (int k0 = 0; k0 < 1024; k0 += 64) {
    __syncthreads();
#pragma unroll
    for (int i=0;i<8;i++){
      int idx = i*256 + tid;
      int half = idx >> 10, id2 = idx & 1023;
      int r = id2 >> 3, c8 = (id2 & 7)*8;
      if (half == 0){
        int gm = m0 + r;
        u16x8 v = {0,0,0,0,0,0,0,0};
        if (gm < MROWS) v = *(const u16x8*)(A + (size_t)gm*1024 + k0 + c8);
        *(u16x8*)(&sm.st.a[r*72 + c8]) = v;
      } else {
        const float* src = Bm + (size_t)(n0 + r)*1024 + k0 + c8;
        float4 a4 = *(const float4*)src;
        float4 b4 = *(const float4*)(src + 4);
        ushort4 ha; ha.x=f2h(a4.x); ha.y=f2h(a4.y); ha.z=f2h(a4.z); ha.w=f2h(a4.w);
        ushort4 hb; hb.x=f2h(b4.x); hb.y=f2h(b4.y); hb.z=f2h(b4.z); hb.w=f2h(b4.w);
        *(ushort4*)(&sm.st.b[r*72 + c8]) = ha;
        *(ushort4*)(&sm.st.b[r*72 + c8 + 4]) = hb;
      }
    }
    __syncthreads();
#pragma unroll
    for (int kk = 0; kk < 64; kk += 32) {
      f16x8 af[4], bfr[4];
      int krow = kk + ((lane >> 4) << 3);
#pragma unroll
      for (int m4=0;m4<4;m4++)
        af[m4] = *(const f16x8*)(&sm.st.a[(wm*64 + m4*16 + (lane & 15))*72 + krow]);
#pragma unroll
      for (int n4=0;n4<4;n4++)
        bfr[n4] = *(const f16x8*)(&sm.st.b[(wn*64 + n4*16 + (lane & 15))*72 + krow]);
#pragma unroll
      for (int m4=0;m4<4;m4++)
#pragma unroll
        for (int n4=0;n4<4;n4++)
          acc[m4][n4] = __builtin_amdgcn_mfma_f32_16x16x32_f16(af[m4], bfr[n4], acc[m4][n4], 0,0,0);
    }
  }
  __syncthreads();
#pragma unroll
  for (int m4=0;m4<4;m4++)
#pragma unroll
    for (int n4=0;n4<4;n4++)
#pragma unroll
      for (int i=0;i<4;i++){
        int row = wm*64 + m4*16 + ((lane>>4)<<2) + i;
        int col = wn*64 + n4*16 + (lane&15);
        sm.cc[row*128 + col] = acc[m4][n4][i];
      }
  __syncthreads();

  if (tid < 128) {
    int row = tid, gm = m0 + row;
    if (gm < MROWS) {
      float mx = -1e30f;
      for (int j=0;j<128;j++){
        int col = (row + j) & 127;
        float x = sm.cc[row*128+col] + bias[n0+col];
        mx = fmaxf(mx, x);
      }
      float sum = 0.f;
      for (int j=0;j<128;j++){
        int col = (row + j) & 127;
        float x = sm.cc[row*128+col] + bias[n0+col];
        sum += expf(x - mx);
      }
      pm[(size_t)gm*NVB + n0/128] = mx;
      ps[(size_t)gm*NVB + n0/128] = sum;
      int g = ids[gm + 64];
      unsigned d = (unsigned)(g - n0);
      if (d < 128u) gl[gm] = sm.cc[row*128 + (int)d] + bias[g];
    }
  }
}

// ---------------- final reduce ----------------
__global__ void k_reduce(const float* __restrict__ pm, const float* __restrict__ ps,
                         const float* __restrict__ gl, const int* __restrict__ ids,
                         float* __restrict__ out)
{
  int b = blockIdx.x, tid = threadIdx.x;
  int lane = tid & 63, w = tid >> 6;
  __shared__ float wacc[4];
  float accum = 0.f;
  for (int t = w; t < TSTEPS; t += 4) {
    int r = t*64 + b;
    const float* pmr = pm + (size_t)r*NVB;
    const float* psr = ps + (size_t)r*NVB;
    float mx = -1e30f;
    for (int p2 = lane; p2 < NVB; p2 += 64) mx = fmaxf(mx, pmr[p2]);
#pragma unroll
    for (int off=32; off; off>>=1) mx = fmaxf(mx, __shfl_xor(mx, off));
    float sm = 0.f;
    for (int p2 = lane; p2 < NVB; p2 += 64) sm += psr[p2] * expf(pmr[p2] - mx);
#pragma unroll
    for (int off=32; off; off>>=1) sm += __shfl_xor(sm, off);
    if (lane == 0) {
      int g = ids[r + 64];
      if (g != 0) accum += gl[r] - (mx + logf(sm));
    }
  }
  if (lane == 0) wacc[w] = accum;
  __syncthreads();
  if (tid == 0) out[b] = wacc[0]+wacc[1]+wacc[2]+wacc[3];
}

// ---------------- host ----------------
extern "C" void kernel_launch(void* const* d_in, const int* in_sizes, int n_in,
                              void* d_out, int out_size, void* d_ws, size_t ws_size,
                              hipStream_t stream)
{
  const int*   ids  = (const int*)d_in[0];
  const float* vc   = (const float*)d_in[1];
  const float* h0   = (const float*)d_in[2];
  const float* c0   = (const float*)d_in[3];
  const float* Etgt = (const float*)d_in[4];
  const float* Watt = (const float*)d_in[5];
  const float* batt = (const float*)d_in[6];
  const float* Wih  = (const float*)d_in[7];
  const float* Whh  = (const float*)d_in[8];
  const float* Wu   = (const float*)d_in[9];
  const float* Wv   = (const float*)d_in[10];
  const float* bv   = (const float*)d_in[11];
  float* out = (float*)d_out;

  char* p = (char*)d_ws;
  auto alloc = [&](size_t bytes)->char* {
    char* r = p; p += (bytes + 255) & ~(size_t)255; return r;
  };
  u32* flags = (u32*)alloc(32768);
  u16* Yh    = (u16*)alloc((size_t)8192*512*2);
  u16* Yl    = (u16*)alloc((size_t)8192*512*2);
  u16* WYh   = (u16*)alloc((size_t)4096*512*2);
  u16* WYl   = (u16*)alloc((size_t)4096*512*2);
  u16* Wuh16 = (u16*)alloc((size_t)1024*1024*2);
  float* Wcat= (float*)alloc((size_t)2048*2048*4);
  u8* ep     = (u8*)alloc((size_t)64*256*1024);
  u8* vuu    = (u8*)alloc((size_t)64*256*1024);
  u16* comb  = (u16*)alloc((size_t)8192*1024*2);
  u16* gY    = (u16*)alloc((size_t)8192*4096*2);
  u16* hfbuf = (u16*)alloc((size_t)2*65536*2);
  u16* ofbuf = (u16*)alloc(65536*2);
  float* ebuf= (float*)alloc((size_t)64*256*4);
  float* phB = (float*)alloc((size_t)64*1024*4);
  float* pm  = (float*)alloc((size_t)MROWS*NVB*4);
  float* ps  = (float*)alloc((size_t)MROWS*NVB*4);
  float* gl  = (float*)alloc((size_t)MROWS*4);

  p_init<<<288, 256, 0, stream>>>(h0, hfbuf, ofbuf, flags);
  p_wcat<<<(2048*2048)/256, 256, 0, stream>>>(Watt, Wu, Wcat);
  p_wy<<<dim3(2, 4096), 256, 0, stream>>>(Wih, WYh, WYl);
  p_wuh<<<dim3(4, 1024), 256, 0, stream>>>(Wu, Wuh16);
  p_y<<<dim3(2, 8192), 256, 0, stream>>>(ids, Etgt, Yh, Yl);

  k_gemm32<<<dim3(16, 128), 256, 0, stream>>>(vc, Wcat, batt, ep, vuu);
  k_gy<<<dim3(32, 64), 256, 0, stream>>>(Yh, Yl, WYh, WYl, gY);

  k_loop<<<NBLK, 256, 0, stream>>>(Wih, Whh, c0, Wuh16, gY, ep, vuu,
                                   hfbuf, ofbuf, ebuf, phB, comb, flags);

  k_gemm16<<<dim3(NVB, 64), 256, 0, stream>>>(comb, Wv, bv, pm, ps, gl, ids);
  k_reduce<<<64, 256, 0, stream>>>(pm, ps, gl, ids, out);
}

// Round 12
// 12884.534 us; speedup vs baseline: 1.1746x; 1.0066x over previous
//
#include <hip/hip_runtime.h>
#include <hip/hip_bf16.h>

#define TSTEPS 127
#define NBLK 256
#define NVB 250      // 32000/128
#define MROWS 8128   // 127*64

typedef unsigned short u16;
typedef unsigned int u32;
typedef unsigned long long u64;
typedef unsigned char u8;
typedef _Float16 f16;
typedef __attribute__((ext_vector_type(8))) short bf16x8;
typedef __attribute__((ext_vector_type(8))) _Float16 f16x8;
typedef __attribute__((ext_vector_type(8))) unsigned short u16x8;
typedef __attribute__((ext_vector_type(4))) float f32x4;
typedef __attribute__((ext_vector_type(2))) float f32x2;

__device__ __forceinline__ u16 f2h(float f){ f16 h=(f16)f; u16 r; __builtin_memcpy(&r,&h,2); return r; }
__device__ __forceinline__ float h2f(u16 u){ f16 h; __builtin_memcpy(&h,&u,2); return (float)h; }
__device__ __forceinline__ float us2f(u16 u){ union{float f;u32 i;}v; v.i=(u32)u<<16; return v.f; }
__device__ __forceinline__ u16 f2us(float f){ __hip_bfloat16 h=__float2bfloat16(f); u16 r; __builtin_memcpy(&r,&h,2); return r; }
__device__ __forceinline__ void split2(float x, u16& hi, u16& lo){
  u16 h = f2us(x); lo = f2us(x - us2f(h)); hi = h;
}

// ---- agent-scope relaxed atomics for mutable shared state ----
__device__ __forceinline__ u64 ldg64(const u64* p){
  return __hip_atomic_load((u64*)p, __ATOMIC_RELAXED, __HIP_MEMORY_SCOPE_AGENT);
}
__device__ __forceinline__ float ldgf(const float* p){
  return __hip_atomic_load((float*)p, __ATOMIC_RELAXED, __HIP_MEMORY_SCOPE_AGENT);
}
__device__ __forceinline__ void stg64(u64* p, u64 v){
  __hip_atomic_store(p, v, __ATOMIC_RELAXED, __HIP_MEMORY_SCOPE_AGENT);
}
__device__ __forceinline__ void stg32(u32* p, u32 v){
  __hip_atomic_store(p, v, __ATOMIC_RELAXED, __HIP_MEMORY_SCOPE_AGENT);
}
__device__ __forceinline__ void stgf(float* p, float v){
  __hip_atomic_store(p, v, __ATOMIC_RELAXED, __HIP_MEMORY_SCOPE_AGENT);
}
__device__ __forceinline__ f16x8 mk8h(u64 a, u64 b){
  union { u64 q[2]; f16x8 v; } u; u.q[0]=a; u.q[1]=b; return u.v;
}

// centralized two-hop barrier: blocks store arrival flags; ONLY block 0's wave 0
// polls them (256 loads/round) and publishes one epoch word; all other blocks
// have ONE thread polling the epoch. Poll traffic ~250x lower than all-spin.
__device__ __forceinline__ void gbar(u32* flags, u32 token){
  asm volatile("s_waitcnt vmcnt(0) lgkmcnt(0)" ::: "memory");
  __syncthreads();
  if (threadIdx.x == 0)
    __hip_atomic_store(&flags[blockIdx.x*32], token, __ATOMIC_RELAXED, __HIP_MEMORY_SCOPE_AGENT);
  if (blockIdx.x == 0){
    if (threadIdx.x < 64){
      const int l = threadIdx.x;
      for (;;){
        bool ok = true;
#pragma unroll
        for (int i=0;i<4;i++)
          ok &= (__hip_atomic_load(&flags[(l*4+i)*32], __ATOMIC_RELAXED, __HIP_MEMORY_SCOPE_AGENT) >= token);
        if (__all(ok)) break;
        __builtin_amdgcn_s_sleep(2);
      }
      if (threadIdx.x == 0)
        __hip_atomic_store(&flags[8192], token, __ATOMIC_RELAXED, __HIP_MEMORY_SCOPE_AGENT);
    }
  } else {
    if (threadIdx.x == 0){
      while (__hip_atomic_load(&flags[8192], __ATOMIC_RELAXED, __HIP_MEMORY_SCOPE_AGENT) < token)
        __builtin_amdgcn_s_sleep(2);
    }
  }
  __syncthreads();
}

// ---------------- prep kernels ----------------
__global__ void p_wcat(const float* __restrict__ Watt, const float* __restrict__ Wu,
                       float* __restrict__ Wcat){
  int idx = blockIdx.x*256 + threadIdx.x;      // 2048*2048
  int n = idx >> 11, k = idx & 2047;
  Wcat[idx] = (n < 1024) ? Watt[idx] : Wu[(size_t)(n-1024)*3072 + k];
}

// WY: Y-part of Wih in j'-order (j' = jj*4+g, j = g*1024+jj), split hi/lo (for k_gy)
__global__ void p_wy(const float* __restrict__ Wih, u16* __restrict__ WYh, u16* __restrict__ WYl){
  int k = blockIdx.x*256 + threadIdx.x;        // 512
  int rp = blockIdx.y;                         // 4096
  int j = (rp & 3)*1024 + (rp >> 2);
  float v = Wih[(size_t)j*1536 + 1024 + k];
  u16 hi, lo; split2(v, hi, lo);
  WYh[(size_t)rp*512 + k] = hi; WYl[(size_t)rp*512 + k] = lo;
}

__global__ void p_wuh(const float* __restrict__ Wu, u16* __restrict__ Wh){
  int k = blockIdx.x*256 + threadIdx.x;        // 1024
  int j = blockIdx.y;                          // 1024
  Wh[(size_t)j*1024 + k] = f2h(Wu[(size_t)j*3072 + 2048 + k]);
}

__global__ void p_y(const int* __restrict__ ids, const float* __restrict__ Etgt,
                    u16* __restrict__ Yh, u16* __restrict__ Yl){
  int e0 = blockIdx.x*256 + threadIdx.x;       // 512
  int row = blockIdx.y;                        // 8192
  int id = ids[row];
  float v = Etgt[(size_t)id*512 + e0];
  u16 hi, lo; split2(v, hi, lo);
  Yh[(size_t)row*512 + e0] = hi; Yl[(size_t)row*512 + e0] = lo;
}

__global__ void p_init(const float* __restrict__ h0,
                       u16* __restrict__ hf, u16* __restrict__ of,
                       u32* __restrict__ flags){
  int idx = blockIdx.x*256 + threadIdx.x;
  if (idx < 65536){
    float hv = h0[idx];
    hf[idx] = f2h(hv);     // parity-0 buffer
    of[idx] = 0;
  } else if (idx < 65536 + 8448){
    flags[idx - 65536] = 0;
  }
}

// ---------------- enc_proj + Vu GEMM (fp32 in, FP8 out): M=16384 N=2048 K=2048 ----
union SharedU {
  struct { u16 a[128*72]; u16 b[128*72]; } st;
  float cc[128*128];
};

__global__ __launch_bounds__(256) void k_gemm32(
    const float* __restrict__ A, const float* __restrict__ Bm,
    const float* __restrict__ bias, u8* __restrict__ ep, u8* __restrict__ vu)
{
  __shared__ SharedU sm;
  const int tid = threadIdx.x;
  const int lane = tid & 63, w = tid >> 6;
  const int wm = w >> 1, wn = w & 1;
  int lw = blockIdx.y * gridDim.x + blockIdx.x;       // 2048
  int swz = (lw & 7)*256 + (lw >> 3);
  const int n0 = (swz & 15) * 128, m0 = (swz >> 4) * 128;
  f32x4 acc[4][4];
#pragma unroll
  for (int i=0;i<4;i++)
#pragma unroll
    for (int j=0;j<4;j++) acc[i][j] = (f32x4)(0.f);

  for (int k0 = 0; k0 < 2048; k0 += 64) {
    __syncthreads();
#pragma unroll
    for (int i=0;i<8;i++){
      int idx = tid + i*256;
      int r = idx >> 4, c4 = idx & 15;
      float4 va = *(const float4*)(&A[(size_t)(m0+r)*2048 + k0 + c4*4]);
      ushort4 sa; sa.x=f2h(va.x); sa.y=f2h(va.y); sa.z=f2h(va.z); sa.w=f2h(va.w);
      *(ushort4*)(&sm.st.a[r*72 + c4*4]) = sa;
      float4 vb = *(const float4*)(&Bm[(size_t)(n0+r)*2048 + k0 + c4*4]);
      ushort4 sb; sb.x=f2h(vb.x); sb.y=f2h(vb.y); sb.z=f2h(vb.z); sb.w=f2h(vb.w);
      *(ushort4*)(&sm.st.b[r*72 + c4*4]) = sb;
    }
    __syncthreads();
#pragma unroll
    for (int kk = 0; kk < 64; kk += 32) {
      f16x8 af[4], bfr[4];
      int krow = kk + ((lane >> 4) << 3);
#pragma unroll
      for (int m4=0;m4<4;m4++)
        af[m4] = *(const f16x8*)(&sm.st.a[(wm*64 + m4*16 + (lane & 15))*72 + krow]);
#pragma unroll
      for (int n4=0;n4<4;n4++)
        bfr[n4] = *(const f16x8*)(&sm.st.b[(wn*64 + n4*16 + (lane & 15))*72 + krow]);
#pragma unroll
      for (int m4=0;m4<4;m4++)
#pragma unroll
        for (int n4=0;n4<4;n4++)
          acc[m4][n4] = __builtin_amdgcn_mfma_f32_16x16x32_f16(af[m4], bfr[n4], acc[m4][n4], 0,0,0);
    }
  }
  __syncthreads();
#pragma unroll
  for (int m4=0;m4<4;m4++)
#pragma unroll
    for (int n4=0;n4<4;n4++)
#pragma unroll
      for (int i=0;i<4;i++){
        int row = wm*64 + m4*16 + ((lane>>4)<<2) + i;
        int col = wn*64 + n4*16 + (lane&15);
        sm.cc[row*128 + col] = acc[m4][n4][i];
      }
  __syncthreads();
  for (int idx = tid*2; idx < 128*128; idx += 512) {
    int row = idx >> 7, col = idx & 127;
    int gm = m0 + row, gn = n0 + col;
    float v0 = sm.cc[idx], v1 = sm.cc[idx+1];
    if (gn < 1024) {
      v0 += bias[gn]; v1 += bias[gn+1];
      int pk = __builtin_amdgcn_cvt_pk_fp8_f32(v0, v1, 0, false);
      *(u16*)(ep + (size_t)gm*1024 + gn) = (u16)(pk & 0xffff);
    } else {
      int pk = __builtin_amdgcn_cvt_pk_fp8_f32(v0, v1, 0, false);
      *(u16*)(vu + (size_t)gm*1024 + (gn-1024)) = (u16)(pk & 0xffff);
    }
  }
}

// ---------------- gY GEMM: gY[(t*64+b)][j'] = Y[t,b,:]·WY[j',:] -> f16 ----
__global__ __launch_bounds__(256) void k_gy(
    const u16* __restrict__ Ah, const u16* __restrict__ Al,
    const u16* __restrict__ Bh, const u16* __restrict__ Bl,
    u16* __restrict__ gY)
{
  __shared__ u16 sah[128*40], sal[128*40], sbh[128*40], sbl[128*40];
  const int tid = threadIdx.x;
  const int lane = tid & 63, w = tid >> 6;
  const int wm = w >> 1, wn = w & 1;
  const int l15 = lane & 15, q8 = (lane>>4)*8;
  int lw = blockIdx.y * gridDim.x + blockIdx.x;       // 2048
  int swz = (lw & 7)*256 + (lw >> 3);
  const int n0 = (swz & 31)*128, m0 = (swz >> 5)*128;
  f32x4 acc[4][4];
#pragma unroll
  for (int i=0;i<4;i++)
#pragma unroll
    for (int j=0;j<4;j++) acc[i][j] = (f32x4)(0.f);

  for (int k0 = 0; k0 < 512; k0 += 32){
    __syncthreads();
#pragma unroll
    for (int i=0;i<8;i++){
      int idx = i*256 + tid;          // 2048 = 4 mats x 512 u16x8
      int mat = idx >> 9, sub = idx & 511;
      int r = sub >> 2, c8 = (sub & 3)*8;
      const u16* src = (mat==0)?Ah:(mat==1)?Al:(mat==2)?Bh:Bl;
      size_t base = (mat<2 ? (size_t)(m0+r)*512 : (size_t)(n0+r)*512) + k0 + c8;
      u16x8 v = *(const u16x8*)(src + base);
      u16* dst = (mat==0)?sah:(mat==1)?sal:(mat==2)?sbh:sbl;
      *(u16x8*)(&dst[r*40 + c8]) = v;
    }
    __syncthreads();
    bf16x8 ah[4], al2[4], bh[4], bl2[4];
#pragma unroll
    for (int m4=0;m4<4;m4++){
      ah[m4]  = *(const bf16x8*)(&sah[(wm*64+m4*16+l15)*40 + q8]);
      al2[m4] = *(const bf16x8*)(&sal[(wm*64+m4*16+l15)*40 + q8]);
    }
#pragma unroll
    for (int n4=0;n4<4;n4++){
      bh[n4]  = *(const bf16x8*)(&sbh[(wn*64+n4*16+l15)*40 + q8]);
      bl2[n4] = *(const bf16x8*)(&sbl[(wn*64+n4*16+l15)*40 + q8]);
    }
#pragma unroll
    for (int m4=0;m4<4;m4++)
#pragma unroll
      for (int n4=0;n4<4;n4++){
        acc[m4][n4] = __builtin_amdgcn_mfma_f32_16x16x32_bf16(ah[m4],  bh[n4],  acc[m4][n4], 0,0,0);
        acc[m4][n4] = __builtin_amdgcn_mfma_f32_16x16x32_bf16(al2[m4], bh[n4],  acc[m4][n4], 0,0,0);
        acc[m4][n4] = __builtin_amdgcn_mfma_f32_16x16x32_bf16(ah[m4],  bl2[n4], acc[m4][n4], 0,0,0);
      }
  }
#pragma unroll
  for (int m4=0;m4<4;m4++)
#pragma unroll
    for (int n4=0;n4<4;n4++)
#pragma unroll
      for (int i=0;i<4;i++){
        int gm = m0 + wm*64 + m4*16 + ((lane>>4)<<2) + i;
        int gn = n0 + wn*64 + n4*16 + l15;
        gY[(size_t)gm*4096 + gn] = f2h(acc[m4][n4][i]);
      }
}

// ---------------- persistent recurrence kernel (r11 structure) ----------------
struct LoopShared {
  u16 wg[32*2048];                       // f16 weights, byte ^= ((row&7)<<4)
  union {
    struct { float psum[2][64][8]; u32 hstage[32][4]; } p1;
    struct { float al[256]; float pared[4][256]; float red[8]; } p3;
  } u;
};

__global__ __launch_bounds__(256, 1) void k_loop(
    const float* __restrict__ Wih, const float* __restrict__ Whh,
    const float* __restrict__ c0g,
    const u16* __restrict__ Wuh16, const u16* __restrict__ gY,
    const u8* __restrict__ ep, const u8* __restrict__ vuu,
    u16* __restrict__ hf, u16* __restrict__ of,
    float* __restrict__ ebuf, float* __restrict__ phB,
    u16* __restrict__ comb, u32* __restrict__ flags)
{
  __shared__ LoopShared sh;
  const int tid = threadIdx.x, blk = blockIdx.x;
  const int lane = tid & 63, w = tid >> 6;
  const int l15 = lane & 15, q = lane >> 4;
  const int jb = blk >> 1, bhalf = blk & 1;
  const int bsub = w & 1, khalf = w >> 1;
  const int b = bhalf*32 + bsub*16 + l15;

  // one-time: 32 j'-rows of [Wih_o | Whh] as f16 into LDS
  for (int i = tid; i < 32*512; i += 256){
    int r = i >> 9, c4 = i & 511;
    int jp = jb*32 + r;
    int j  = (jp & 3)*1024 + (jp >> 2);
    float4 v = (c4 < 256) ? *(const float4*)(&Wih[(size_t)j*1536 + c4*4])
                          : *(const float4*)(&Whh[(size_t)j*1024 + (c4-256)*4]);
    ushort4 hh; hh.x=f2h(v.x); hh.y=f2h(v.y); hh.z=f2h(v.z); hh.w=f2h(v.w);
    int byteoff = (r*4096 + c4*8) ^ ((r & 7) << 4);
    *(ushort4*)((char*)sh.wg + byteoff) = hh;
  }
  float cReg0 = 0.f, cReg1 = 0.f;
  if (w < 2){
    cReg0 = c0g[(size_t)b*1024 + jb*8 + q];
    cReg1 = c0g[(size_t)b*1024 + jb*8 + 4 + q];
  }
  __syncthreads();
  const char* wgc = (const char*)sh.wg;

  for (int t = 0; t < TSTEPS; ++t){
    const int p = t & 1;
    const u16* hP = hf + p*65536;
    u16* hN = hf + (p^1)*65536;

    // ======== P1: gates MFMA (f16, LDS weights) + LSTM ========
    {
      float gy0[4], gy1[4];
      if (w < 2){
        const u16* gb = gY + ((size_t)(t*64 + b))*4096 + jb*32 + q*4;
        ushort4 g0 = *(const ushort4*)(gb);
        ushort4 g1 = *(const ushort4*)(gb + 16);
        gy0[0]=h2f(g0.x); gy0[1]=h2f(g0.y); gy0[2]=h2f(g0.z); gy0[3]=h2f(g0.w);
        gy1[0]=h2f(g1.x); gy1[1]=h2f(g1.y); gy1[2]=h2f(g1.z); gy1[3]=h2f(g1.w);
      }
      const u64* xsrc = (khalf ? (const u64*)hP : (const u64*)of) + b*256;
      f32x4 acc0 = (f32x4)(0.f), acc1 = (f32x4)(0.f);
#pragma unroll 4
      for (int kt = 0; kt < 32; ++kt){
        int base = khalf*2048 + kt*64 + q*16;
        int w0 = (l15*4096 + base) ^ ((l15 & 7) << 4);
        f16x8 wf0 = *(const f16x8*)(wgc + w0);
        f16x8 wf1 = *(const f16x8*)(wgc + w0 + 65536);   // row+16, same (row&7)
        const u64* px = xsrc + kt*8 + q*2;
        f16x8 xf = mk8h(ldg64(px), ldg64(px+1));
        acc0 = __builtin_amdgcn_mfma_f32_16x16x32_f16(wf0, xf, acc0, 0,0,0);
        acc1 = __builtin_amdgcn_mfma_f32_16x16x32_f16(wf1, xf, acc1, 0,0,0);
      }
      if (w >= 2){
        float* ps_ = &sh.u.p1.psum[w-2][lane][0];
#pragma unroll
        for (int i=0;i<4;i++){ ps_[i] = acc0[i]; ps_[4+i] = acc1[i]; }
      }
      __syncthreads();
      if (w < 2){
        const float* ps_ = &sh.u.p1.psum[w][lane][0];
        u16 h0b, h1b;
        {
          float gi = acc0[0]+ps_[0]+gy0[0], gf = acc0[1]+ps_[1]+gy0[1];
          float gg = acc0[2]+ps_[2]+gy0[2], go = acc0[3]+ps_[3]+gy0[3];
          gi = 1.f/(1.f+expf(-gi)); gf = 1.f/(1.f+expf(-gf));
          gg = tanhf(gg);           go = 1.f/(1.f+expf(-go));
          float cn = gf*cReg0 + gi*gg; cReg0 = cn;
          h0b = f2h(go*tanhf(cn));
        }
        {
          float gi = acc1[0]+ps_[4]+gy1[0], gf = acc1[1]+ps_[5]+gy1[1];
          float gg = acc1[2]+ps_[6]+gy1[2], go = acc1[3]+ps_[7]+gy1[3];
          gi = 1.f/(1.f+expf(-gi)); gf = 1.f/(1.f+expf(-gf));
          gg = tanhf(gg);           go = 1.f/(1.f+expf(-go));
          float cn = gf*cReg1 + gi*gg; cReg1 = cn;
          h1b = f2h(go*tanhf(cn));
        }
        int bl = bsub*16 + l15;
        u16* hs = (u16*)sh.u.p1.hstage;
        hs[bl*8 + q] = h0b;
        hs[bl*8 + 4 + q] = h1b;
      }
      __syncthreads();
      if (tid < 128){
        int bl = tid >> 2, sub = tid & 3;
        u32 v = sh.u.p1.hstage[bl][sub];
        stg32((u32*)hN + (size_t)(bhalf*32 + bl)*512 + jb*4 + sub, v);
      }
    }
    gbar(flags, (u32)(t*3 + 1));

    // ======== P2: ph MFMA (blocks 0..15) | e_t fp8 (blocks 16..255) ========
    if (blk < 16){
      const int jrow = blk*64 + w*16 + l15;
      const u16* wp = Wuh16 + (size_t)jrow*1024;
      f32x4 pacc[4];
#pragma unroll
      for (int i=0;i<4;i++) pacc[i] = (f32x4)(0.f);
#pragma unroll 2
      for (int kt = 0; kt < 32; ++kt){
        f16x8 bfr = *(const f16x8*)(wp + kt*32 + q*8);
#pragma unroll
        for (int m=0;m<4;m++){
          const u64* px = (const u64*)hN + (size_t)(m*16+l15)*256 + kt*8 + q*2;
          f16x8 xf = mk8h(ldg64(px), ldg64(px+1));
          pacc[m] = __builtin_amdgcn_mfma_f32_16x16x32_f16(xf, bfr, pacc[m], 0,0,0);
        }
      }
#pragma unroll
      for (int m=0;m<4;m++)
#pragma unroll
        for (int i=0;i<4;i++){
          int bb = m*16 + q*4 + i;
          stgf(phB + (size_t)bb*1024 + jrow, pacc[m][i]);
        }
    } else {
      for (int u2 = blk - 16; u2 < 256; u2 += 240){
        const int ab = u2 >> 2, sl = u2 & 3;
        // per-lane h slice k = l15*64 .. +64 (f16)
        float hr[64];
        {
          const u64* hp = (const u64*)hN + (size_t)ab*256 + l15*16;
#pragma unroll
          for (int i=0;i<16;i++){
            union{u64 q_; u16 s[4];} uu; uu.q_ = ldg64(hp + i);
#pragma unroll
            for (int e=0;e<4;e++) hr[i*4+e] = h2f(uu.s[e]);
          }
        }
        const int rbase = sl*64 + w*16;
#pragma unroll
        for (int rg = 0; rg < 4; rg++){
          int s = rbase + rg*4 + q;
          const uint4* row = (const uint4*)(ep + ((size_t)(ab*256 + s))*1024 + l15*64);
          float a = 0.f;
#pragma unroll
          for (int c=0;c<4;c++){
            uint4 v = row[c];
#pragma unroll
            for (int e=0;e<4;e++){
              u32 wv = (&v.x)[e];
              f32x2 lo = __builtin_amdgcn_cvt_pk_f32_fp8(wv, false);
              f32x2 hi = __builtin_amdgcn_cvt_pk_f32_fp8(wv, true);
              int bse = c*16 + e*4;
              a += lo.x*hr[bse] + lo.y*hr[bse+1] + hi.x*hr[bse+2] + hi.y*hr[bse+3];
            }
          }
          a += __shfl_xor(a, 1); a += __shfl_xor(a, 2);
          a += __shfl_xor(a, 4); a += __shfl_xor(a, 8);
          if (l15 == 0) stgf(ebuf + ab*256 + s, a);
        }
      }
    }
    gbar(flags, (u32)(t*3 + 2));

    // ======== P3: softmax + pa (fp8 vuu) + o_t ========
    {
      const int ab = blk >> 2, jq = blk & 3;
      float x = ldgf(ebuf + ab*256 + tid);
      float m_ = x;
#pragma unroll
      for (int off=32; off; off>>=1) m_ = fmaxf(m_, __shfl_xor(m_, off));
      if (lane == 0) sh.u.p3.red[w] = m_;
      __syncthreads();
      m_ = fmaxf(fmaxf(sh.u.p3.red[0],sh.u.p3.red[1]), fmaxf(sh.u.p3.red[2],sh.u.p3.red[3]));
      float pv = expf(x - m_);
      float sv = pv;
#pragma unroll
      for (int off=32; off; off>>=1) sv += __shfl_xor(sv, off);
      if (lane == 0) sh.u.p3.red[4+w] = sv;
      __syncthreads();
      float tot = sh.u.p3.red[4]+sh.u.p3.red[5]+sh.u.p3.red[6]+sh.u.p3.red[7];
      sh.u.p3.al[tid] = pv / tot;
      __syncthreads();
      float a0=0.f, a1=0.f, a2=0.f, a3=0.f;
      const u8* vb = vuu + ((size_t)(ab*256) + w*64)*1024 + jq*256 + lane*4;
      for (int s2=0; s2<64; s2++){
        float aa = sh.u.p3.al[w*64 + s2];
        u32 v = *(const u32*)(vb + (size_t)s2*1024);
        f32x2 lo = __builtin_amdgcn_cvt_pk_f32_fp8(v, false);
        f32x2 hi = __builtin_amdgcn_cvt_pk_f32_fp8(v, true);
        a0 += aa*lo.x; a1 += aa*lo.y; a2 += aa*hi.x; a3 += aa*hi.y;
      }
      float4 o4; o4.x=a0; o4.y=a1; o4.z=a2; o4.w=a3;
      *(float4*)(&sh.u.p3.pared[w][lane*4]) = o4;
      __syncthreads();
      if (tid < 64){
        const int col = tid*4;
        union{u64 q_; u16 s[4];} uo;
        ushort4 cw;
#pragma unroll
        for (int i=0;i<4;i++){
          float pa = sh.u.p3.pared[0][col+i] + sh.u.p3.pared[1][col+i]
                   + sh.u.p3.pared[2][col+i] + sh.u.p3.pared[3][col+i];
          pa += ldgf(phB + (size_t)ab*1024 + jq*256 + col + i);
          u16 ob = f2h(tanhf(pa));
          uo.s[i] = ob; (&cw.x)[i] = ob;
        }
        stg64((u64*)of + (size_t)ab*256 + jq*64 + tid, uo.q_);
        *(ushort4*)(comb + (size_t)(t*64 + ab)*1024 + jq*256 + col) = cw;
      }
    }
    gbar(flags, (u32)(t*3 + 3));
  }
}

// ---------------- vocab GEMM (comb f16, Wv fp32 converted in-loader) ----------------
__global__ __launch_bounds__(256) void k_gemm16(
    const u16* __restrict__ A, const float* __restrict__ Bm,
    const float* __restrict__ bias,
    float* __restrict__ pm, float* __restrict__ ps,
    float* __restrict__ gl, const int* __restrict__ ids)
{
  __shared__ SharedU sm;
  const int tid = threadIdx.x;
  const int lane = tid & 63, w = tid >> 6;
  const int wm = w >> 1, wn = w & 1;
  int lw = blockIdx.y * 250 + blockIdx.x;        // 16000
  int swz = (lw & 7)*2000 + (lw >> 3);
  const int n0 = (swz % 250) * 128, m0 = (swz / 250) * 128;
  f32x4 acc[4][4];
#pragma unroll
  for (int i=0;i<4;i++)
#pragma unroll
    for (int j=0;j<4;j++) acc[i][j] = (f32x4)(0.f);

  for (int k0 = 0; k0 < 1024; k0 += 64) {
    __syncthreads();
#pragma unroll
    for (int i=0;i<8;i++){
      int idx = i*256 + tid;
      int half = idx >> 10, id2 = idx & 1023;
      int r = id2 >> 3, c8 = (id2 & 7)*8;
      if (half == 0){
        int gm = m0 + r;
        u16x8 v = {0,0,0,0,0,0,0,0};
        if (gm < MROWS) v = *(const u16x8*)(A + (size_t)gm*1024 + k0 + c8);
        *(u16x8*)(&sm.st.a[r*72 + c8]) = v;
      } else {
        const float* src = Bm + (size_t)(n0 + r)*1024 + k0 + c8;
        float4 a4 = *(const float4*)src;
        float4 b4 = *(const float4*)(src + 4);
        ushort4 ha; ha.x=f2h(a4.x); ha.y=f2h(a4.y); ha.z=f2h(a4.z); ha.w=f2h(a4.w);
        ushort4 hb; hb.x=f2h(b4.x); hb.y=f2h(b4.y); hb.z=f2h(b4.z); hb.w=f2h(b4.w);
        *(ushort4*)(&sm.st.b[r*72 + c8]) = ha;
        *(ushort4*)(&sm.st.b[r*72 + c8 + 4]) = hb;
      }
    }
    __syncthreads();
#pragma unroll
    for (int kk = 0; kk < 64; kk += 32) {
      f16x8 af[4], bfr[4];
      int krow = kk + ((lane >> 4) << 3);
#pragma unroll
      for (int m4=0;m4<4;m4++)
        af[m4] = *(const f16x8*)(&sm.st.a[(wm*64 + m4*16 + (lane & 15))*72 + krow]);
#pragma unroll
      for (int n4=0;n4<4;n4++)
        bfr[n4] = *(const f16x8*)(&sm.st.b[(wn*64 + n4*16 + (lane & 15))*72 + krow]);
#pragma unroll
      for (int m4=0;m4<4;m4++)
#pragma unroll
        for (int n4=0;n4<4;n4++)
          acc[m4][n4] = __builtin_amdgcn_mfma_f32_16x16x32_f16(af[m4], bfr[n4], acc[m4][n4], 0,0,0);
    }
  }
  __syncthreads();
#pragma unroll
  for (int m4=0;m4<4;m4++)
#pragma unroll
    for (int n4=0;n4<4;n4++)
#pragma unroll
      for (int i=0;i<4;i++){
        int row = wm*64 + m4*16 + ((lane>>4)<<2) + i;
        int col = wn*64 + n4*16 + (lane&15);
        sm.cc[row*128 + col] = acc[m4][n4][i];
      }
  __syncthreads();

  if (tid < 128) {
    int row = tid, gm = m0 + row;
    if (gm < MROWS) {
      float mx = -1e30f;
      for (int j=0;j<128;j++){
        int col = (row + j) & 127;
        float x = sm.cc[row*128+col] + bias[n0+col];
        mx = fmaxf(mx, x);
      }
      float sum = 0.f;
      for (int j=0;j<128;j++){
        int col = (row + j) & 127;
        float x = sm.cc[row*128+col] + bias[n0+col];
        sum += expf(x - mx);
      }
      pm[(size_t)gm*NVB + n0/128] = mx;
      ps[(size_t)gm*NVB + n0/128] = sum;
      int g = ids[gm + 64];
      unsigned d = (unsigned)(g - n0);
      if (d < 128u) gl[gm] = sm.cc[row*128 + (int)d] + bias[g];
    }
  }
}

// ---------------- final reduce ----------------
__global__ void k_reduce(const float* __restrict__ pm, const float* __restrict__ ps,
                         const float* __restrict__ gl, const int* __restrict__ ids,
                         float* __restrict__ out)
{
  int b = blockIdx.x, tid = threadIdx.x;
  int lane = tid & 63, w = tid >> 6;
  __shared__ float wacc[4];
  float accum = 0.f;
  for (int t = w; t < TSTEPS; t += 4) {
    int r = t*64 + b;
    const float* pmr = pm + (size_t)r*NVB;
    const float* psr = ps + (size_t)r*NVB;
    float mx = -1e30f;
    for (int p2 = lane; p2 < NVB; p2 += 64) mx = fmaxf(mx, pmr[p2]);
#pragma unroll
    for (int off=32; off; off>>=1) mx = fmaxf(mx, __shfl_xor(mx, off));
    float sm = 0.f;
    for (int p2 = lane; p2 < NVB; p2 += 64) sm += psr[p2] * expf(pmr[p2] - mx);
#pragma unroll
    for (int off=32; off; off>>=1) sm += __shfl_xor(sm, off);
    if (lane == 0) {
      int g = ids[r + 64];
      if (g != 0) accum += gl[r] - (mx + logf(sm));
    }
  }
  if (lane == 0) wacc[w] = accum;
  __syncthreads();
  if (tid == 0) out[b] = wacc[0]+wacc[1]+wacc[2]+wacc[3];
}

// ---------------- host ----------------
extern "C" void kernel_launch(void* const* d_in, const int* in_sizes, int n_in,
                              void* d_out, int out_size, void* d_ws, size_t ws_size,
                              hipStream_t stream)
{
  const int*   ids  = (const int*)d_in[0];
  const float* vc   = (const float*)d_in[1];
  const float* h0   = (const float*)d_in[2];
  const float* c0   = (const float*)d_in[3];
  const float* Etgt = (const float*)d_in[4];
  const float* Watt = (const float*)d_in[5];
  const float* batt = (const float*)d_in[6];
  const float* Wih  = (const float*)d_in[7];
  const float* Whh  = (const float*)d_in[8];
  const float* Wu   = (const float*)d_in[9];
  const float* Wv   = (const float*)d_in[10];
  const float* bv   = (const float*)d_in[11];
  float* out = (float*)d_out;

  char* p = (char*)d_ws;
  auto alloc = [&](size_t bytes)->char* {
    char* r = p; p += (bytes + 255) & ~(size_t)255; return r;
  };
  u32* flags = (u32*)alloc(36864);               // 8192 barrier flags + epoch word
  u16* Yh    = (u16*)alloc((size_t)8192*512*2);
  u16* Yl    = (u16*)alloc((size_t)8192*512*2);
  u16* WYh   = (u16*)alloc((size_t)4096*512*2);
  u16* WYl   = (u16*)alloc((size_t)4096*512*2);
  u16* Wuh16 = (u16*)alloc((size_t)1024*1024*2);
  float* Wcat= (float*)alloc((size_t)2048*2048*4);
  u8* ep     = (u8*)alloc((size_t)64*256*1024);
  u8* vuu    = (u8*)alloc((size_t)64*256*1024);
  u16* comb  = (u16*)alloc((size_t)8192*1024*2);
  u16* gY    = (u16*)alloc((size_t)8192*4096*2);
  u16* hfbuf = (u16*)alloc((size_t)2*65536*2);
  u16* ofbuf = (u16*)alloc(65536*2);
  float* ebuf= (float*)alloc((size_t)64*256*4);
  float* phB = (float*)alloc((size_t)64*1024*4);
  float* pm  = (float*)alloc((size_t)MROWS*NVB*4);
  float* ps  = (float*)alloc((size_t)MROWS*NVB*4);
  float* gl  = (float*)alloc((size_t)MROWS*4);

  p_init<<<289, 256, 0, stream>>>(h0, hfbuf, ofbuf, flags);
  p_wcat<<<(2048*2048)/256, 256, 0, stream>>>(Watt, Wu, Wcat);
  p_wy<<<dim3(2, 4096), 256, 0, stream>>>(Wih, WYh, WYl);
  p_wuh<<<dim3(4, 1024), 256, 0, stream>>>(Wu, Wuh16);
  p_y<<<dim3(2, 8192), 256, 0, stream>>>(ids, Etgt, Yh, Yl);

  k_gemm32<<<dim3(16, 128), 256, 0, stream>>>(vc, Wcat, batt, ep, vuu);
  k_gy<<<dim3(32, 64), 256, 0, stream>>>(Yh, Yl, WYh, WYl, gY);

  k_loop<<<NBLK, 256, 0, stream>>>(Wih, Whh, c0, Wuh16, gY, ep, vuu,
                                   hfbuf, ofbuf, ebuf, phB, comb, flags);

  k_gemm16<<<dim3(NVB, 64), 256, 0, stream>>>(comb, Wv, bv, pm, ps, gl, ids);
  k_reduce<<<64, 256, 0, stream>>>(pm, ps, gl, ids, out);
}